// Round 11
// baseline (285.867 us; speedup 1.0000x reference)
//
#include <hip/hip_runtime.h>
#include <hip/hip_bf16.h>

#define DEV __device__ __forceinline__

typedef __bf16 bf16x8 __attribute__((ext_vector_type(8)));
typedef float f32x4 __attribute__((ext_vector_type(4)));
typedef float f32x16 __attribute__((ext_vector_type(16)));
using u16 = unsigned short;
using u32 = unsigned int;

static constexpr int S = 2048;
static constexpr int D = 1024;
static constexpr float SCQ = 0.125f * 1.44269504088896340736f;  // 1/sqrt(64)*log2(e)

DEV u16 f2bf(float f) {  // RNE
  unsigned u = __builtin_bit_cast(unsigned, f);
  u += 0x7fffu + ((u >> 16) & 1u);
  return (u16)(u >> 16);
}
DEV u16 f2bfr(float f) {  // round-half-up (cheap)
  return (u16)((__builtin_bit_cast(u32, f) + 0x8000u) >> 16);
}
// two f32 -> packed bf16x2, round-half-up: 2 int adds + one v_perm
DEV u32 pk2(float a, float b) {
  u32 ua = __builtin_bit_cast(u32, a) + 0x8000u;
  u32 ub = __builtin_bit_cast(u32, b) + 0x8000u;
  return __builtin_amdgcn_perm(ub, ua, 0x07060302);  // {lo: a, hi: b}
}

// async global->LDS DMA, 16B per lane. LDS dest is wave-uniform base + lane*16
// (dest must be linear in lane order; global src is per-lane).
DEV void gl16(const u16* __restrict__ g, u16* l) {
  __builtin_amdgcn_global_load_lds((const __attribute__((address_space(1))) u32*)g,
                                   (__attribute__((address_space(3))) u32*)l, 16, 0, 0);
}

// ---- merged prep: x pack + W_qkv transpose + W_out transpose (one dispatch) ----
__global__ __launch_bounds__(256) void k_prep(const float* __restrict__ x, u16* __restrict__ Xb,
                                              const float* __restrict__ Wqkv, u16* __restrict__ WqkvT,
                                              const float* __restrict__ Wout, u16* __restrict__ WoutT) {
  __shared__ float t[32][33];
  const int bid = blockIdx.x;
  const int tid = threadIdx.x;
  if (bid < 4096) {  // pack x: 4096 blocks x 256 threads x 1 float4
    const int i = bid * 256 + tid;
    const float4 v = reinterpret_cast<const float4*>(x)[i];
    ushort4 o;
    o.x = f2bf(v.x); o.y = f2bf(v.y); o.z = f2bf(v.z); o.w = f2bf(v.w);
    reinterpret_cast<ushort4*>(Xb)[i] = o;
    return;
  }
  const float* in;
  u16* out;
  int R, C, bx, by;
  if (bid < 4096 + 3072) {  // W_qkv [1024][3072] -> [3072][1024]
    const int b = bid - 4096;
    in = Wqkv; out = WqkvT; R = 1024; C = 3072;
    bx = b % 96; by = b / 96;
  } else {  // W_out [1024][1024] -> [1024][1024]^T
    const int b = bid - 7168;
    in = Wout; out = WoutT; R = 1024; C = 1024;
    bx = b & 31; by = b >> 5;
  }
  const int tx = tid & 31, ty = tid >> 5;
  const int c0 = bx * 32, r0 = by * 32;
  for (int i = ty; i < 32; i += 8)
    t[i][tx] = in[(size_t)(r0 + i) * C + c0 + tx];
  __syncthreads();
  for (int i = ty; i < 32; i += 8)
    out[(size_t)(c0 + i) * R + r0 + tx] = f2bf(t[tx][i]);
}

// ---- 128x128 bf16 GEMM (QKV): dbuf gl_lds pipeline + LT overlay + XCD swizzle ----
__global__ __launch_bounds__(256, 5) void k_gemm0(const u16* __restrict__ A, const u16* __restrict__ Bt,
                                                  const float* __restrict__ bias, int M, int N, int K,
                                                  u16* __restrict__ Qb, u16* __restrict__ Kb,
                                                  u16* __restrict__ Vt) {
  constexpr int TN = 128, NJ = 4;
  constexpr int ASZ = 2 * 128 * 32 * 2;  // 16384
  __shared__ __align__(16) char smem[ASZ + 2 * TN * 32 * 2];  // 32768
  auto As = reinterpret_cast<u16(*)[128][32]>(smem);
  auto Bs = reinterpret_cast<u16(*)[TN][32]>(smem + ASZ);
  auto LT = reinterpret_cast<u16(*)[136]>(smem);  // epilogue-only overlay, 64x136x2 = 17408B
  const int tid = threadIdx.x;
  const int lane = tid & 63, wave = tid >> 6;
  const int l15 = lane & 15, quad = lane >> 4;
  // XCD swizzle: nwg = 24*32 = 768, chunk = 96 (4 M-rows of 24)
  const int bid0 = blockIdx.x + 24 * blockIdx.y;
  const int bid = (bid0 & 7) * 96 + (bid0 >> 3);
  const int m0 = (bid / 24) * 128, n0 = (bid % 24) * TN;
  const int wm = (wave >> 1) * 64, wn = (wave & 1) * (TN / 2);
  const int lr = lane >> 2;  // 0..15: row within a 16-row staging group
  const int lcs = ((((lane & 3) - (lane >> 3)) & 3)) * 8;   // inverse-swizzled source col
  const int sq = ((quad + (l15 >> 1)) & 3) * 8;             // swizzled read col

  f32x4 acc[4][NJ];
#pragma unroll
  for (int i = 0; i < 4; i++)
#pragma unroll
    for (int j = 0; j < NJ; j++) acc[i][j] = (f32x4){0.f, 0.f, 0.f, 0.f};

  const u16* Aw0 = &A[(size_t)(m0 + wave * 32 + lr) * K + lcs];
  const u16* Aw1 = &A[(size_t)(m0 + wave * 32 + 16 + lr) * K + lcs];
  const u16* Bw0 = &Bt[(size_t)(n0 + wave * 32 + lr) * K + lcs];
  const u16* Bw1 = &Bt[(size_t)(n0 + wave * 32 + 16 + lr) * K + lcs];

  gl16(Aw0, &As[0][wave * 32][0]);
  gl16(Aw1, &As[0][wave * 32 + 16][0]);
  gl16(Bw0, &Bs[0][wave * 32][0]);
  gl16(Bw1, &Bs[0][wave * 32 + 16][0]);

  int cur = 0;
#pragma unroll 2
  for (int kk = 0; kk < K; kk += 32, cur ^= 1) {
    __syncthreads();
    if (kk + 32 < K) {
      gl16(Aw0 + kk + 32, &As[cur ^ 1][wave * 32][0]);
      gl16(Aw1 + kk + 32, &As[cur ^ 1][wave * 32 + 16][0]);
      gl16(Bw0 + kk + 32, &Bs[cur ^ 1][wave * 32][0]);
      gl16(Bw1 + kk + 32, &Bs[cur ^ 1][wave * 32 + 16][0]);
    }
    bf16x8 af[4], bfv[NJ];
#pragma unroll
    for (int i = 0; i < 4; i++)
      af[i] = *reinterpret_cast<const bf16x8*>(&As[cur][wm + i * 16 + l15][sq]);
#pragma unroll
    for (int j = 0; j < NJ; j++)
      bfv[j] = *reinterpret_cast<const bf16x8*>(&Bs[cur][wn + j * 16 + l15][sq]);
#pragma unroll
    for (int i = 0; i < 4; i++)
#pragma unroll
      for (int j = 0; j < NJ; j++)
        acc[i][j] = __builtin_amdgcn_mfma_f32_16x16x32_bf16(af[i], bfv[j], acc[i][j], 0, 0, 0);
  }

  if (n0 >= 2048) {
    // ---- V blocks: LDS transpose (LT overlays As/Bs) -> coalesced stores along s ----
    const int b = m0 >> 11, sbase = m0 & 2047;
#pragma unroll
    for (int p = 0; p < 2; p++) {
      __syncthreads();
      if ((wave & 1) == p) {
#pragma unroll
        for (int j = 0; j < NJ; j++) {
          const int n = n0 + wn + j * 16 + l15;
          const float vb = bias[n];
#pragma unroll
          for (int i = 0; i < 4; i++) {
            uint2 pw;
            pw.x = pk2(acc[i][j][0] + vb, acc[i][j][1] + vb);
            pw.y = pk2(acc[i][j][2] + vb, acc[i][j][3] + vb);
            *reinterpret_cast<uint2*>(&LT[j * 16 + l15][wm + i * 16 + quad * 4]) = pw;
          }
        }
      }
      __syncthreads();
      const int h = ((n0 - 2048) >> 6) + p;
      const int bh = b * 16 + h;
      const int nl = tid >> 2, cc = (tid & 3) * 32;
      u16* dst = &Vt[((size_t)bh * 64 + nl) * S + sbase + cc];
#pragma unroll
      for (int k = 0; k < 4; k++)
        reinterpret_cast<uint4*>(dst)[k] = *reinterpret_cast<const uint4*>(&LT[nl][cc + k * 8]);
    }
  } else {
    // ---- Q/K blocks: direct stores (coalesced over l15) ----
#pragma unroll
    for (int i = 0; i < 4; i++) {
#pragma unroll
      for (int j = 0; j < NJ; j++) {
#pragma unroll
        for (int r = 0; r < 4; r++) {
          const int m = m0 + wm + i * 16 + quad * 4 + r;
          const int n = n0 + wn + j * 16 + l15;
          const float v = acc[i][j][r] + bias[n];
          const int h = (n >> 6) & 15, dh = n & 63;
          const int b = m >> 11, s = m & 2047;
          const int bh = b * 16 + h;
          if (n < 1024) Qb[((size_t)bh * S + s) * 64 + dh] = f2bfr(v * SCQ);
          else          Kb[((size_t)bh * S + s) * 64 + dh] = f2bfr(v);
        }
      }
    }
  }
}

// ---- out-proj GEMM: 128x64 tile, BK=64 + bijective XCD swizzle (512=8*64) ----
__global__ __launch_bounds__(256, 2) void k_gemm2(const u16* __restrict__ A, const u16* __restrict__ Bt,
                                                  const float* __restrict__ bias, float* __restrict__ outF) {
  constexpr int K = 1024, N = 1024;
  constexpr int ASZ = 2 * 128 * 64 * 2;  // 32768
  __shared__ __align__(16) char smem[ASZ + 2 * 64 * 64 * 2];  // 49152
  auto As = reinterpret_cast<u16(*)[128][64]>(smem);
  auto Bs = reinterpret_cast<u16(*)[64][64]>(smem + ASZ);
  const int tid = threadIdx.x;
  const int lane = tid & 63, wave = tid >> 6;
  const int l15 = lane & 15, quad = lane >> 4;
  // XCD swizzle: nwg = 16*32 = 512, chunk = 64
  const int bid0 = blockIdx.x + 16 * blockIdx.y;
  const int bid = (bid0 & 7) * 64 + (bid0 >> 3);
  const int m0 = (bid >> 4) * 128, n0 = (bid & 15) * 64;
  const int wm = (wave >> 1) * 64, wn = (wave & 1) * 32;
  const int srow = lane >> 3;                       // 0..7 row within 8-row chunk
  const int scol = ((lane & 7) ^ srow) * 8;         // inverse-swizzled source col

  f32x4 acc[4][2];
#pragma unroll
  for (int i = 0; i < 4; i++)
#pragma unroll
    for (int j = 0; j < 2; j++) acc[i][j] = (f32x4){0.f, 0.f, 0.f, 0.f};

  // staging pointers: A 16 chunks of 8 rows (4/wave), B 8 chunks (2/wave)
  const u16* Ap[4];
  const u16* Bp[2];
#pragma unroll
  for (int c = 0; c < 4; c++)
    Ap[c] = &A[(size_t)(m0 + (wave * 4 + c) * 8 + srow) * K + scol];
#pragma unroll
  for (int c = 0; c < 2; c++)
    Bp[c] = &Bt[(size_t)(n0 + (wave * 2 + c) * 8 + srow) * K + scol];

  // prologue: stage K-tile 0 into buf 0
#pragma unroll
  for (int c = 0; c < 4; c++) gl16(Ap[c], &As[0][(wave * 4 + c) * 8][0]);
#pragma unroll
  for (int c = 0; c < 2; c++) gl16(Bp[c], &Bs[0][(wave * 2 + c) * 8][0]);

  int cur = 0;
#pragma unroll 2
  for (int kk = 0; kk < K; kk += 64, cur ^= 1) {
    __syncthreads();  // buf[cur] staged; prev reads of buf[cur^1] done
    if (kk + 64 < K) {
#pragma unroll
      for (int c = 0; c < 4; c++) gl16(Ap[c] + kk + 64, &As[cur ^ 1][(wave * 4 + c) * 8][0]);
#pragma unroll
      for (int c = 0; c < 2; c++) gl16(Bp[c] + kk + 64, &Bs[cur ^ 1][(wave * 2 + c) * 8][0]);
    }
#pragma unroll
    for (int ks = 0; ks < 2; ks++) {
      const int sc = ((ks * 4 + quad) ^ (l15 & 7)) * 8;  // swizzled read col
      bf16x8 af[4], bfv[2];
#pragma unroll
      for (int i = 0; i < 4; i++)
        af[i] = *reinterpret_cast<const bf16x8*>(&As[cur][wm + i * 16 + l15][sc]);
#pragma unroll
      for (int j = 0; j < 2; j++)
        bfv[j] = *reinterpret_cast<const bf16x8*>(&Bs[cur][wn + j * 16 + l15][sc]);
#pragma unroll
      for (int i = 0; i < 4; i++)
#pragma unroll
        for (int j = 0; j < 2; j++)
          acc[i][j] = __builtin_amdgcn_mfma_f32_16x16x32_bf16(af[i], bfv[j], acc[i][j], 0, 0, 0);
    }
  }

#pragma unroll
  for (int i = 0; i < 4; i++)
#pragma unroll
    for (int j = 0; j < 2; j++)
#pragma unroll
      for (int r = 0; r < 4; r++) {
        const int m = m0 + wm + i * 16 + quad * 4 + r;
        const int n = n0 + wn + j * 16 + l15;
        outF[(size_t)m * N + n] = acc[i][j][r] + bias[n];
      }
}

// ---- flash attention: QBLK=64, 2 waves, 128 threads (4 independent blocks/CU).
// R10 had 2 blocks/CU of 4 barrier-locked waves -> serial QK->exp2->permlane->PV
// chain had nothing to hide under (MfmaUtil 27%). Same 8 waves/CU, but 2-wave
// barrier scope + independent blocks per SIMD fill each other's stalls.
// XCD swizzle (1024=8*128). T5 setprio. T12 in-register P (verified R9).
__global__ __launch_bounds__(128, 2) void k_attn(const u16* __restrict__ Qb,
                                                 const u16* __restrict__ Kb,
                                                 const u16* __restrict__ Vt,
                                                 u16* __restrict__ attnB) {
  __shared__ u16 Ks[64][72];     // [key][dh]       9.2KB
  __shared__ u16 Vs[64][72];     // [dh][key_local] 9.2KB
  __shared__ u16 Pl[2][32][72];  // epilogue-only (O staging) 9.2KB
  const int tid = threadIdx.x;
  const int lane = tid & 63, wave = tid >> 6;  // wave in {0,1}
  const int l31 = lane & 31, hi = lane >> 5;
  // XCD swizzle: nwg = 32*32 = 1024, chunk = 128 (4 bh of 32 q-blocks per XCD)
  const int bid0 = blockIdx.x + 32 * blockIdx.y;
  const int bid = (bid0 & 7) * 128 + (bid0 >> 3);
  const int bh = bid >> 5;
  const int q0 = (bid & 31) * 64;
  const u16* Qh = Qb + (size_t)bh * S * 64;
  const u16* Kh = Kb + (size_t)bh * S * 64;
  const u16* Vh = Vt + (size_t)bh * 64 * S;
  const int qrow = q0 + wave * 32 + l31;
  bf16x8 qf[4];  // Q (pre-scaled by SCQ) as B-operand: n = lane&31 = q
#pragma unroll
  for (int f = 0; f < 4; f++)
    qf[f] = *reinterpret_cast<const bf16x8*>(&Qh[(size_t)qrow * 64 + f * 16 + hi * 8]);

  const int r0 = tid >> 3, c0 = (tid & 7) * 8;  // staging: 16 rows/pass, 4 passes

  float li = 0.f;
  f32x16 o0, o1;  // O d-tiles: d = dt*32 + (reg&3)+8*(reg>>2)+4*hi
#pragma unroll
  for (int r = 0; r < 16; r++) { o0[r] = 0.f; o1[r] = 0.f; }

  uint4 pk[4], pv[4];
#pragma unroll
  for (int c = 0; c < 4; c++) {
    pk[c] = *reinterpret_cast<const uint4*>(&Kh[(size_t)(r0 + 16 * c) * 64 + c0]);
    pv[c] = *reinterpret_cast<const uint4*>(&Vh[(size_t)(r0 + 16 * c) * S + c0]);
  }

  for (int kb = 0; kb < S / 64; kb++) {
    __syncthreads();  // prev tile consumed
#pragma unroll
    for (int c = 0; c < 4; c++) {
      *reinterpret_cast<uint4*>(&Ks[r0 + 16 * c][c0]) = pk[c];
      *reinterpret_cast<uint4*>(&Vs[r0 + 16 * c][c0]) = pv[c];
    }
    __syncthreads();  // tile ready
    if (kb + 1 < S / 64) {
      const u16* Kn = Kh + (size_t)(kb + 1) * 64 * 64;
#pragma unroll
      for (int c = 0; c < 4; c++) {
        pk[c] = *reinterpret_cast<const uint4*>(&Kn[(size_t)(r0 + 16 * c) * 64 + c0]);
        pv[c] = *reinterpret_cast<const uint4*>(&Vh[(size_t)(r0 + 16 * c) * S + (kb + 1) * 64 + c0]);
      }
    }
    // QK^T: 2 key-tiles x 4 k-steps (Q pre-scaled -> z is log2-domain score)
    f32x16 z[2];
    __builtin_amdgcn_s_setprio(1);
#pragma unroll
    for (int kt = 0; kt < 2; kt++) {
#pragma unroll
      for (int r = 0; r < 16; r++) z[kt][r] = 0.f;
#pragma unroll
      for (int f = 0; f < 4; f++) {
        const bf16x8 a = *reinterpret_cast<const bf16x8*>(&Ks[kt * 32 + l31][f * 16 + hi * 8]);
        z[kt] = __builtin_amdgcn_mfma_f32_32x32x16_bf16(a, qf[f], z[kt], 0, 0, 0);
      }
    }
    __builtin_amdgcn_s_setprio(0);
    // p = exp2(z); accumulate denominator (4-way partials)
    float s0 = 0.f, s1 = 0.f, s2 = 0.f, s3 = 0.f;
#pragma unroll
    for (int kt = 0; kt < 2; kt++)
#pragma unroll
      for (int r = 0; r < 16; r++) {
        const float p = __builtin_amdgcn_exp2f(z[kt][r]);
        z[kt][r] = p;
        if ((r & 3) == 0) s0 += p; else if ((r & 3) == 1) s1 += p;
        else if ((r & 3) == 2) s2 += p; else s3 += p;
      }
    li += (s0 + s1) + (s2 + s3);
    // PV: A = V^T rows, B = P built in-register (pk2 + permlane32_swap)
    __builtin_amdgcn_s_setprio(1);
#pragma unroll
    for (int kt = 0; kt < 2; kt++) {
#pragma unroll
      for (int s = 0; s < 2; s++) {
        u32 w0 = pk2(z[kt][s * 8 + 0], z[kt][s * 8 + 1]);
        u32 w2 = pk2(z[kt][s * 8 + 4], z[kt][s * 8 + 5]);
        asm("v_permlane32_swap_b32 %0, %1" : "+v"(w0), "+v"(w2));
        u32 w1 = pk2(z[kt][s * 8 + 2], z[kt][s * 8 + 3]);
        u32 w3 = pk2(z[kt][s * 8 + 6], z[kt][s * 8 + 7]);
        asm("v_permlane32_swap_b32 %0, %1" : "+v"(w1), "+v"(w3));
        uint4 wv;
        wv.x = w0; wv.y = w1; wv.z = w2; wv.w = w3;
        const bf16x8 bp = __builtin_bit_cast(bf16x8, wv);
        const int f = kt * 2 + s;
        const bf16x8 av0 = *reinterpret_cast<const bf16x8*>(&Vs[l31][f * 16 + hi * 8]);
        const bf16x8 av1 = *reinterpret_cast<const bf16x8*>(&Vs[32 + l31][f * 16 + hi * 8]);
        o0 = __builtin_amdgcn_mfma_f32_32x32x16_bf16(av0, bp, o0, 0, 0, 0);
        o1 = __builtin_amdgcn_mfma_f32_32x32x16_bf16(av1, bp, o1, 0, 0, 0);
      }
    }
    __builtin_amdgcn_s_setprio(0);
  }
  li += __shfl_xor(li, 32);
  const float inv = 1.f / li;
  // O -> Pl[q][d] (wave-private), then coalesced store
#pragma unroll
  for (int dt = 0; dt < 2; dt++) {
    const f32x16& od = dt ? o1 : o0;
#pragma unroll
    for (int g = 0; g < 4; g++) {
      uint2 ow;
      ow.x = pk2(od[g * 4 + 0] * inv, od[g * 4 + 1] * inv);
      ow.y = pk2(od[g * 4 + 2] * inv, od[g * 4 + 3] * inv);
      *reinterpret_cast<uint2*>(&Pl[wave][l31][dt * 32 + g * 8 + hi * 4]) = ow;
    }
  }
  const int b = bh >> 4, h = bh & 15;
  const int mbase = b * S + q0 + wave * 32;
  const int qr = lane >> 1, ch = (lane & 1) * 32;
  u16* dst = &attnB[(size_t)(mbase + qr) * D + h * 64 + ch];
#pragma unroll
  for (int c = 0; c < 4; c++)
    reinterpret_cast<uint4*>(dst)[c] = *reinterpret_cast<const uint4*>(&Pl[wave][qr][ch + c * 8]);
}

extern "C" void kernel_launch(void* const* d_in, const int* in_sizes, int n_in,
                              void* d_out, int out_size, void* d_ws, size_t ws_size,
                              hipStream_t stream) {
  const float* x = (const float*)d_in[0];
  const float* Wqkv = (const float*)d_in[1];
  const float* bqkv = (const float*)d_in[2];
  const float* Wout = (const float*)d_in[3];
  const float* bout = (const float*)d_in[4];
  float* out = (float*)d_out;

  char* p = (char*)d_ws;
  u16* WoutT = (u16*)p; p += (size_t)1024 * 1024 * 2;     // 2MB  (live thru gemm2)
  u16* attnB = (u16*)p; p += (size_t)4096 * 1024 * 2;     // 8MB  (live thru gemm2)
  u16* Xb = (u16*)p;    p += (size_t)4096 * 1024 * 2;     // 8MB  (dead after gemm0)
  u16* WqkvT = (u16*)p; p += (size_t)3072 * 1024 * 2;     // 6MB  (dead after gemm0)
  u16* Vt = (u16*)p;    p += (size_t)32 * 64 * 2048 * 2;  // 8MB  (dead after attn)
  u16* Qb = (u16*)p;    p += (size_t)32 * 2048 * 64 * 2;  // 8MB  (dead after attn)
  u16* Kb = (u16*)p;    p += (size_t)32 * 2048 * 64 * 2;  // 8MB  (dead after attn)

  k_prep<<<4096 + 3072 + 1024, 256, 0, stream>>>(x, Xb, Wqkv, WqkvT, Wout, WoutT);
  k_gemm0<<<dim3(3072 / 128, 4096 / 128), 256, 0, stream>>>(
      Xb, WqkvT, bqkv, 4096, 3072, 1024, Qb, Kb, Vt);
  k_attn<<<dim3(32, 32), 128, 0, stream>>>(Qb, Kb, Vt, attnB);
  k_gemm2<<<dim3(1024 / 64, 4096 / 128), 256, 0, stream>>>(attnB, WoutT, bout, out);
}

// Round 12
// 191.505 us; speedup vs baseline: 1.4927x; 1.4927x over previous
//
#include <hip/hip_runtime.h>
#include <hip/hip_bf16.h>

#define DEV __device__ __forceinline__

typedef __bf16 bf16x8 __attribute__((ext_vector_type(8)));
typedef float f32x4 __attribute__((ext_vector_type(4)));
typedef float f32x16 __attribute__((ext_vector_type(16)));
using u16 = unsigned short;
using u32 = unsigned int;

static constexpr int S = 2048;
static constexpr int D = 1024;
static constexpr float SCQ = 0.125f * 1.44269504088896340736f;  // 1/sqrt(64)*log2(e)

DEV u16 f2bf(float f) {  // RNE
  unsigned u = __builtin_bit_cast(unsigned, f);
  u += 0x7fffu + ((u >> 16) & 1u);
  return (u16)(u >> 16);
}
DEV u16 f2bfr(float f) {  // round-half-up (cheap)
  return (u16)((__builtin_bit_cast(u32, f) + 0x8000u) >> 16);
}
// two f32 -> packed bf16x2, round-half-up: 2 int adds + one v_perm
DEV u32 pk2(float a, float b) {
  u32 ua = __builtin_bit_cast(u32, a) + 0x8000u;
  u32 ub = __builtin_bit_cast(u32, b) + 0x8000u;
  return __builtin_amdgcn_perm(ub, ua, 0x07060302);  // {lo: a, hi: b}
}

// async global->LDS DMA, 16B per lane. LDS dest is wave-uniform base + lane*16
// (dest must be linear in lane order; global src is per-lane).
DEV void gl16(const u16* __restrict__ g, u16* l) {
  __builtin_amdgcn_global_load_lds((const __attribute__((address_space(1))) u32*)g,
                                   (__attribute__((address_space(3))) u32*)l, 16, 0, 0);
}

// ---- merged prep: x pack + W_qkv transpose + W_out transpose (one dispatch) ----
__global__ __launch_bounds__(256) void k_prep(const float* __restrict__ x, u16* __restrict__ Xb,
                                              const float* __restrict__ Wqkv, u16* __restrict__ WqkvT,
                                              const float* __restrict__ Wout, u16* __restrict__ WoutT) {
  __shared__ float t[32][33];
  const int bid = blockIdx.x;
  const int tid = threadIdx.x;
  if (bid < 4096) {  // pack x: 4096 blocks x 256 threads x 1 float4
    const int i = bid * 256 + tid;
    const float4 v = reinterpret_cast<const float4*>(x)[i];
    ushort4 o;
    o.x = f2bf(v.x); o.y = f2bf(v.y); o.z = f2bf(v.z); o.w = f2bf(v.w);
    reinterpret_cast<ushort4*>(Xb)[i] = o;
    return;
  }
  const float* in;
  u16* out;
  int R, C, bx, by;
  if (bid < 4096 + 3072) {  // W_qkv [1024][3072] -> [3072][1024]
    const int b = bid - 4096;
    in = Wqkv; out = WqkvT; R = 1024; C = 3072;
    bx = b % 96; by = b / 96;
  } else {  // W_out [1024][1024] -> [1024][1024]^T
    const int b = bid - 7168;
    in = Wout; out = WoutT; R = 1024; C = 1024;
    bx = b & 31; by = b >> 5;
  }
  const int tx = tid & 31, ty = tid >> 5;
  const int c0 = bx * 32, r0 = by * 32;
  for (int i = ty; i < 32; i += 8)
    t[i][tx] = in[(size_t)(r0 + i) * C + c0 + tx];
  __syncthreads();
  for (int i = ty; i < 32; i += 8)
    out[(size_t)(c0 + i) * R + r0 + tx] = f2bf(t[tx][i]);
}

// ---- 128x128 bf16 GEMM (QKV): dbuf gl_lds pipeline + LT overlay + XCD swizzle ----
__global__ __launch_bounds__(256, 5) void k_gemm0(const u16* __restrict__ A, const u16* __restrict__ Bt,
                                                  const float* __restrict__ bias, int M, int N, int K,
                                                  u16* __restrict__ Qb, u16* __restrict__ Kb,
                                                  u16* __restrict__ Vt) {
  constexpr int TN = 128, NJ = 4;
  constexpr int ASZ = 2 * 128 * 32 * 2;  // 16384
  __shared__ __align__(16) char smem[ASZ + 2 * TN * 32 * 2];  // 32768
  auto As = reinterpret_cast<u16(*)[128][32]>(smem);
  auto Bs = reinterpret_cast<u16(*)[TN][32]>(smem + ASZ);
  auto LT = reinterpret_cast<u16(*)[136]>(smem);  // epilogue-only overlay, 64x136x2 = 17408B
  const int tid = threadIdx.x;
  const int lane = tid & 63, wave = tid >> 6;
  const int l15 = lane & 15, quad = lane >> 4;
  // XCD swizzle: nwg = 24*32 = 768, chunk = 96 (4 M-rows of 24)
  const int bid0 = blockIdx.x + 24 * blockIdx.y;
  const int bid = (bid0 & 7) * 96 + (bid0 >> 3);
  const int m0 = (bid / 24) * 128, n0 = (bid % 24) * TN;
  const int wm = (wave >> 1) * 64, wn = (wave & 1) * (TN / 2);
  const int lr = lane >> 2;  // 0..15: row within a 16-row staging group
  const int lcs = ((((lane & 3) - (lane >> 3)) & 3)) * 8;   // inverse-swizzled source col
  const int sq = ((quad + (l15 >> 1)) & 3) * 8;             // swizzled read col

  f32x4 acc[4][NJ];
#pragma unroll
  for (int i = 0; i < 4; i++)
#pragma unroll
    for (int j = 0; j < NJ; j++) acc[i][j] = (f32x4){0.f, 0.f, 0.f, 0.f};

  const u16* Aw0 = &A[(size_t)(m0 + wave * 32 + lr) * K + lcs];
  const u16* Aw1 = &A[(size_t)(m0 + wave * 32 + 16 + lr) * K + lcs];
  const u16* Bw0 = &Bt[(size_t)(n0 + wave * 32 + lr) * K + lcs];
  const u16* Bw1 = &Bt[(size_t)(n0 + wave * 32 + 16 + lr) * K + lcs];

  gl16(Aw0, &As[0][wave * 32][0]);
  gl16(Aw1, &As[0][wave * 32 + 16][0]);
  gl16(Bw0, &Bs[0][wave * 32][0]);
  gl16(Bw1, &Bs[0][wave * 32 + 16][0]);

  int cur = 0;
#pragma unroll 2
  for (int kk = 0; kk < K; kk += 32, cur ^= 1) {
    __syncthreads();
    if (kk + 32 < K) {
      gl16(Aw0 + kk + 32, &As[cur ^ 1][wave * 32][0]);
      gl16(Aw1 + kk + 32, &As[cur ^ 1][wave * 32 + 16][0]);
      gl16(Bw0 + kk + 32, &Bs[cur ^ 1][wave * 32][0]);
      gl16(Bw1 + kk + 32, &Bs[cur ^ 1][wave * 32 + 16][0]);
    }
    bf16x8 af[4], bfv[NJ];
#pragma unroll
    for (int i = 0; i < 4; i++)
      af[i] = *reinterpret_cast<const bf16x8*>(&As[cur][wm + i * 16 + l15][sq]);
#pragma unroll
    for (int j = 0; j < NJ; j++)
      bfv[j] = *reinterpret_cast<const bf16x8*>(&Bs[cur][wn + j * 16 + l15][sq]);
#pragma unroll
    for (int i = 0; i < 4; i++)
#pragma unroll
      for (int j = 0; j < NJ; j++)
        acc[i][j] = __builtin_amdgcn_mfma_f32_16x16x32_bf16(af[i], bfv[j], acc[i][j], 0, 0, 0);
  }

  if (n0 >= 2048) {
    // ---- V blocks: LDS transpose (LT overlays As/Bs) -> coalesced stores along s ----
    const int b = m0 >> 11, sbase = m0 & 2047;
#pragma unroll
    for (int p = 0; p < 2; p++) {
      __syncthreads();
      if ((wave & 1) == p) {
#pragma unroll
        for (int j = 0; j < NJ; j++) {
          const int n = n0 + wn + j * 16 + l15;
          const float vb = bias[n];
#pragma unroll
          for (int i = 0; i < 4; i++) {
            uint2 pw;
            pw.x = pk2(acc[i][j][0] + vb, acc[i][j][1] + vb);
            pw.y = pk2(acc[i][j][2] + vb, acc[i][j][3] + vb);
            *reinterpret_cast<uint2*>(&LT[j * 16 + l15][wm + i * 16 + quad * 4]) = pw;
          }
        }
      }
      __syncthreads();
      const int h = ((n0 - 2048) >> 6) + p;
      const int bh = b * 16 + h;
      const int nl = tid >> 2, cc = (tid & 3) * 32;
      u16* dst = &Vt[((size_t)bh * 64 + nl) * S + sbase + cc];
#pragma unroll
      for (int k = 0; k < 4; k++)
        reinterpret_cast<uint4*>(dst)[k] = *reinterpret_cast<const uint4*>(&LT[nl][cc + k * 8]);
    }
  } else {
    // ---- Q/K blocks: direct stores (coalesced over l15) ----
#pragma unroll
    for (int i = 0; i < 4; i++) {
#pragma unroll
      for (int j = 0; j < NJ; j++) {
#pragma unroll
        for (int r = 0; r < 4; r++) {
          const int m = m0 + wm + i * 16 + quad * 4 + r;
          const int n = n0 + wn + j * 16 + l15;
          const float v = acc[i][j][r] + bias[n];
          const int h = (n >> 6) & 15, dh = n & 63;
          const int b = m >> 11, s = m & 2047;
          const int bh = b * 16 + h;
          if (n < 1024) Qb[((size_t)bh * S + s) * 64 + dh] = f2bfr(v * SCQ);
          else          Kb[((size_t)bh * S + s) * 64 + dh] = f2bfr(v);
        }
      }
    }
  }
}

// ---- out-proj GEMM: 128x64 tile, BK=64 + bijective XCD swizzle (512=8*64) ----
__global__ __launch_bounds__(256, 2) void k_gemm2(const u16* __restrict__ A, const u16* __restrict__ Bt,
                                                  const float* __restrict__ bias, float* __restrict__ outF) {
  constexpr int K = 1024, N = 1024;
  constexpr int ASZ = 2 * 128 * 64 * 2;  // 32768
  __shared__ __align__(16) char smem[ASZ + 2 * 64 * 64 * 2];  // 49152
  auto As = reinterpret_cast<u16(*)[128][64]>(smem);
  auto Bs = reinterpret_cast<u16(*)[64][64]>(smem + ASZ);
  const int tid = threadIdx.x;
  const int lane = tid & 63, wave = tid >> 6;
  const int l15 = lane & 15, quad = lane >> 4;
  // XCD swizzle: nwg = 16*32 = 512, chunk = 64
  const int bid0 = blockIdx.x + 16 * blockIdx.y;
  const int bid = (bid0 & 7) * 64 + (bid0 >> 3);
  const int m0 = (bid >> 4) * 128, n0 = (bid & 15) * 64;
  const int wm = (wave >> 1) * 64, wn = (wave & 1) * 32;
  const int srow = lane >> 3;                       // 0..7 row within 8-row chunk
  const int scol = ((lane & 7) ^ srow) * 8;         // inverse-swizzled source col

  f32x4 acc[4][2];
#pragma unroll
  for (int i = 0; i < 4; i++)
#pragma unroll
    for (int j = 0; j < 2; j++) acc[i][j] = (f32x4){0.f, 0.f, 0.f, 0.f};

  // staging pointers: A 16 chunks of 8 rows (4/wave), B 8 chunks (2/wave)
  const u16* Ap[4];
  const u16* Bp[2];
#pragma unroll
  for (int c = 0; c < 4; c++)
    Ap[c] = &A[(size_t)(m0 + (wave * 4 + c) * 8 + srow) * K + scol];
#pragma unroll
  for (int c = 0; c < 2; c++)
    Bp[c] = &Bt[(size_t)(n0 + (wave * 2 + c) * 8 + srow) * K + scol];

  // prologue: stage K-tile 0 into buf 0
#pragma unroll
  for (int c = 0; c < 4; c++) gl16(Ap[c], &As[0][(wave * 4 + c) * 8][0]);
#pragma unroll
  for (int c = 0; c < 2; c++) gl16(Bp[c], &Bs[0][(wave * 2 + c) * 8][0]);

  int cur = 0;
#pragma unroll 2
  for (int kk = 0; kk < K; kk += 64, cur ^= 1) {
    __syncthreads();  // buf[cur] staged; prev reads of buf[cur^1] done
    if (kk + 64 < K) {
#pragma unroll
      for (int c = 0; c < 4; c++) gl16(Ap[c] + kk + 64, &As[cur ^ 1][(wave * 4 + c) * 8][0]);
#pragma unroll
      for (int c = 0; c < 2; c++) gl16(Bp[c] + kk + 64, &Bs[cur ^ 1][(wave * 2 + c) * 8][0]);
    }
#pragma unroll
    for (int ks = 0; ks < 2; ks++) {
      const int sc = ((ks * 4 + quad) ^ (l15 & 7)) * 8;  // swizzled read col
      bf16x8 af[4], bfv[2];
#pragma unroll
      for (int i = 0; i < 4; i++)
        af[i] = *reinterpret_cast<const bf16x8*>(&As[cur][wm + i * 16 + l15][sc]);
#pragma unroll
      for (int j = 0; j < 2; j++)
        bfv[j] = *reinterpret_cast<const bf16x8*>(&Bs[cur][wn + j * 16 + l15][sc]);
#pragma unroll
      for (int i = 0; i < 4; i++)
#pragma unroll
        for (int j = 0; j < 2; j++)
          acc[i][j] = __builtin_amdgcn_mfma_f32_16x16x32_bf16(af[i], bfv[j], acc[i][j], 0, 0, 0);
    }
  }

#pragma unroll
  for (int i = 0; i < 4; i++)
#pragma unroll
    for (int j = 0; j < 2; j++)
#pragma unroll
      for (int r = 0; r < 4; r++) {
        const int m = m0 + wm + i * 16 + quad * 4 + r;
        const int n = n0 + wn + j * 16 + l15;
        outF[(size_t)m * N + n] = acc[i][j][r] + bias[n];
      }
}

// ---- flash attention: QBLK=64, 2 waves, 128 threads (4 independent blocks/CU).
// R11's version of this structure spilled: uint4 pk[4]/pv[4] ARRAYS went to
// scratch (rule #20: WRITE_SIZE 8->170MB at unchanged VGPR=68 — same signature
// as R6). Fix: eight NAMED uint4 scalars, hand-unrolled staging (R10's working
// pattern). XCD swizzle (1024=8*128). T5 setprio. T12 in-register P.
__global__ __launch_bounds__(128, 2) void k_attn(const u16* __restrict__ Qb,
                                                 const u16* __restrict__ Kb,
                                                 const u16* __restrict__ Vt,
                                                 u16* __restrict__ attnB) {
  __shared__ u16 Ks[64][72];     // [key][dh]       9.2KB
  __shared__ u16 Vs[64][72];     // [dh][key_local] 9.2KB
  __shared__ u16 Pl[2][32][72];  // epilogue-only (O staging) 4.6KB
  const int tid = threadIdx.x;
  const int lane = tid & 63, wave = tid >> 6;  // wave in {0,1}
  const int l31 = lane & 31, hi = lane >> 5;
  // XCD swizzle: nwg = 32*32 = 1024, chunk = 128 (4 bh of 32 q-blocks per XCD)
  const int bid0 = blockIdx.x + 32 * blockIdx.y;
  const int bid = (bid0 & 7) * 128 + (bid0 >> 3);
  const int bh = bid >> 5;
  const int q0 = (bid & 31) * 64;
  const u16* Qh = Qb + (size_t)bh * S * 64;
  const u16* Kh = Kb + (size_t)bh * S * 64;
  const u16* Vh = Vt + (size_t)bh * 64 * S;
  const int qrow = q0 + wave * 32 + l31;
  bf16x8 qf[4];  // Q (pre-scaled by SCQ) as B-operand: n = lane&31 = q
#pragma unroll
  for (int f = 0; f < 4; f++)
    qf[f] = *reinterpret_cast<const bf16x8*>(&Qh[(size_t)qrow * 64 + f * 16 + hi * 8]);

  const int r0 = tid >> 3, c0 = (tid & 7) * 8;  // staging: 16 rows/pass, 4 passes

  float li = 0.f;
  f32x16 o0, o1;  // O d-tiles: d = dt*32 + (reg&3)+8*(reg>>2)+4*hi
#pragma unroll
  for (int r = 0; r < 16; r++) { o0[r] = 0.f; o1[r] = 0.f; }

  // NAMED prefetch scalars (arrays spill to scratch — R6/R11 lesson)
  uint4 pka = *reinterpret_cast<const uint4*>(&Kh[(size_t)(r0 +  0) * 64 + c0]);
  uint4 pkb = *reinterpret_cast<const uint4*>(&Kh[(size_t)(r0 + 16) * 64 + c0]);
  uint4 pkc = *reinterpret_cast<const uint4*>(&Kh[(size_t)(r0 + 32) * 64 + c0]);
  uint4 pkd = *reinterpret_cast<const uint4*>(&Kh[(size_t)(r0 + 48) * 64 + c0]);
  uint4 pva = *reinterpret_cast<const uint4*>(&Vh[(size_t)(r0 +  0) * S + c0]);
  uint4 pvb = *reinterpret_cast<const uint4*>(&Vh[(size_t)(r0 + 16) * S + c0]);
  uint4 pvc = *reinterpret_cast<const uint4*>(&Vh[(size_t)(r0 + 32) * S + c0]);
  uint4 pvd = *reinterpret_cast<const uint4*>(&Vh[(size_t)(r0 + 48) * S + c0]);

  for (int kb = 0; kb < S / 64; kb++) {
    __syncthreads();  // prev tile consumed
    *reinterpret_cast<uint4*>(&Ks[r0 +  0][c0]) = pka;
    *reinterpret_cast<uint4*>(&Ks[r0 + 16][c0]) = pkb;
    *reinterpret_cast<uint4*>(&Ks[r0 + 32][c0]) = pkc;
    *reinterpret_cast<uint4*>(&Ks[r0 + 48][c0]) = pkd;
    *reinterpret_cast<uint4*>(&Vs[r0 +  0][c0]) = pva;
    *reinterpret_cast<uint4*>(&Vs[r0 + 16][c0]) = pvb;
    *reinterpret_cast<uint4*>(&Vs[r0 + 32][c0]) = pvc;
    *reinterpret_cast<uint4*>(&Vs[r0 + 48][c0]) = pvd;
    __syncthreads();  // tile ready
    if (kb + 1 < S / 64) {
      const u16* Kn = Kh + (size_t)(kb + 1) * 64 * 64;
      const u16* Vn = Vh + (size_t)(kb + 1) * 64;
      pka = *reinterpret_cast<const uint4*>(&Kn[(size_t)(r0 +  0) * 64 + c0]);
      pkb = *reinterpret_cast<const uint4*>(&Kn[(size_t)(r0 + 16) * 64 + c0]);
      pkc = *reinterpret_cast<const uint4*>(&Kn[(size_t)(r0 + 32) * 64 + c0]);
      pkd = *reinterpret_cast<const uint4*>(&Kn[(size_t)(r0 + 48) * 64 + c0]);
      pva = *reinterpret_cast<const uint4*>(&Vn[(size_t)(r0 +  0) * S + c0]);
      pvb = *reinterpret_cast<const uint4*>(&Vn[(size_t)(r0 + 16) * S + c0]);
      pvc = *reinterpret_cast<const uint4*>(&Vn[(size_t)(r0 + 32) * S + c0]);
      pvd = *reinterpret_cast<const uint4*>(&Vn[(size_t)(r0 + 48) * S + c0]);
    }
    // QK^T: 2 key-tiles x 4 k-steps (Q pre-scaled -> z is log2-domain score)
    f32x16 z[2];
    __builtin_amdgcn_s_setprio(1);
#pragma unroll
    for (int kt = 0; kt < 2; kt++) {
#pragma unroll
      for (int r = 0; r < 16; r++) z[kt][r] = 0.f;
#pragma unroll
      for (int f = 0; f < 4; f++) {
        const bf16x8 a = *reinterpret_cast<const bf16x8*>(&Ks[kt * 32 + l31][f * 16 + hi * 8]);
        z[kt] = __builtin_amdgcn_mfma_f32_32x32x16_bf16(a, qf[f], z[kt], 0, 0, 0);
      }
    }
    __builtin_amdgcn_s_setprio(0);
    // p = exp2(z); accumulate denominator (4-way partials)
    float s0 = 0.f, s1 = 0.f, s2 = 0.f, s3 = 0.f;
#pragma unroll
    for (int kt = 0; kt < 2; kt++)
#pragma unroll
      for (int r = 0; r < 16; r++) {
        const float p = __builtin_amdgcn_exp2f(z[kt][r]);
        z[kt][r] = p;
        if ((r & 3) == 0) s0 += p; else if ((r & 3) == 1) s1 += p;
        else if ((r & 3) == 2) s2 += p; else s3 += p;
      }
    li += (s0 + s1) + (s2 + s3);
    // PV: A = V^T rows, B = P built in-register (pk2 + permlane32_swap)
    __builtin_amdgcn_s_setprio(1);
#pragma unroll
    for (int kt = 0; kt < 2; kt++) {
#pragma unroll
      for (int s = 0; s < 2; s++) {
        u32 w0 = pk2(z[kt][s * 8 + 0], z[kt][s * 8 + 1]);
        u32 w2 = pk2(z[kt][s * 8 + 4], z[kt][s * 8 + 5]);
        asm("v_permlane32_swap_b32 %0, %1" : "+v"(w0), "+v"(w2));
        u32 w1 = pk2(z[kt][s * 8 + 2], z[kt][s * 8 + 3]);
        u32 w3 = pk2(z[kt][s * 8 + 6], z[kt][s * 8 + 7]);
        asm("v_permlane32_swap_b32 %0, %1" : "+v"(w1), "+v"(w3));
        uint4 wv;
        wv.x = w0; wv.y = w1; wv.z = w2; wv.w = w3;
        const bf16x8 bp = __builtin_bit_cast(bf16x8, wv);
        const int f = kt * 2 + s;
        const bf16x8 av0 = *reinterpret_cast<const bf16x8*>(&Vs[l31][f * 16 + hi * 8]);
        const bf16x8 av1 = *reinterpret_cast<const bf16x8*>(&Vs[32 + l31][f * 16 + hi * 8]);
        o0 = __builtin_amdgcn_mfma_f32_32x32x16_bf16(av0, bp, o0, 0, 0, 0);
        o1 = __builtin_amdgcn_mfma_f32_32x32x16_bf16(av1, bp, o1, 0, 0, 0);
      }
    }
    __builtin_amdgcn_s_setprio(0);
  }
  li += __shfl_xor(li, 32);
  const float inv = 1.f / li;
  // O -> Pl[q][d] (wave-private), then coalesced store
#pragma unroll
  for (int dt = 0; dt < 2; dt++) {
    const f32x16& od = dt ? o1 : o0;
#pragma unroll
    for (int g = 0; g < 4; g++) {
      uint2 ow;
      ow.x = pk2(od[g * 4 + 0] * inv, od[g * 4 + 1] * inv);
      ow.y = pk2(od[g * 4 + 2] * inv, od[g * 4 + 3] * inv);
      *reinterpret_cast<uint2*>(&Pl[wave][l31][dt * 32 + g * 8 + hi * 4]) = ow;
    }
  }
  const int b = bh >> 4, h = bh & 15;
  const int mbase = b * S + q0 + wave * 32;
  const int qr = lane >> 1, ch = (lane & 1) * 32;
  u16* dst = &attnB[(size_t)(mbase + qr) * D + h * 64 + ch];
#pragma unroll
  for (int c = 0; c < 4; c++)
    reinterpret_cast<uint4*>(dst)[c] = *reinterpret_cast<const uint4*>(&Pl[wave][qr][ch + c * 8]);
}

extern "C" void kernel_launch(void* const* d_in, const int* in_sizes, int n_in,
                              void* d_out, int out_size, void* d_ws, size_t ws_size,
                              hipStream_t stream) {
  const float* x = (const float*)d_in[0];
  const float* Wqkv = (const float*)d_in[1];
  const float* bqkv = (const float*)d_in[2];
  const float* Wout = (const float*)d_in[3];
  const float* bout = (const float*)d_in[4];
  float* out = (float*)d_out;

  char* p = (char*)d_ws;
  u16* WoutT = (u16*)p; p += (size_t)1024 * 1024 * 2;     // 2MB  (live thru gemm2)
  u16* attnB = (u16*)p; p += (size_t)4096 * 1024 * 2;     // 8MB  (live thru gemm2)
  u16* Xb = (u16*)p;    p += (size_t)4096 * 1024 * 2;     // 8MB  (dead after gemm0)
  u16* WqkvT = (u16*)p; p += (size_t)3072 * 1024 * 2;     // 6MB  (dead after gemm0)
  u16* Vt = (u16*)p;    p += (size_t)32 * 64 * 2048 * 2;  // 8MB  (dead after attn)
  u16* Qb = (u16*)p;    p += (size_t)32 * 2048 * 64 * 2;  // 8MB  (dead after attn)
  u16* Kb = (u16*)p;    p += (size_t)32 * 2048 * 64 * 2;  // 8MB  (dead after attn)

  k_prep<<<4096 + 3072 + 1024, 256, 0, stream>>>(x, Xb, Wqkv, WqkvT, Wout, WoutT);
  k_gemm0<<<dim3(3072 / 128, 4096 / 128), 256, 0, stream>>>(
      Xb, WqkvT, bqkv, 4096, 3072, 1024, Qb, Kb, Vt);
  k_attn<<<dim3(32, 32), 128, 0, stream>>>(Qb, Kb, Vt, attnB);
  k_gemm2<<<dim3(1024 / 64, 4096 / 128), 256, 0, stream>>>(attnB, WoutT, bout, out);
}

// Round 13
// 187.495 us; speedup vs baseline: 1.5247x; 1.0214x over previous
//
#include <hip/hip_runtime.h>
#include <hip/hip_bf16.h>

#define DEV __device__ __forceinline__

typedef __bf16 bf16x8 __attribute__((ext_vector_type(8)));
typedef float f32x4 __attribute__((ext_vector_type(4)));
typedef float f32x16 __attribute__((ext_vector_type(16)));
using u16 = unsigned short;
using u32 = unsigned int;

static constexpr int S = 2048;
static constexpr int D = 1024;
static constexpr float SCQ = 0.125f * 1.44269504088896340736f;  // 1/sqrt(64)*log2(e)

DEV u16 f2bf(float f) {  // RNE
  unsigned u = __builtin_bit_cast(unsigned, f);
  u += 0x7fffu + ((u >> 16) & 1u);
  return (u16)(u >> 16);
}
DEV u16 f2bfr(float f) {  // round-half-up (cheap)
  return (u16)((__builtin_bit_cast(u32, f) + 0x8000u) >> 16);
}
// two f32 -> packed bf16x2, round-half-up: 2 int adds + one v_perm
DEV u32 pk2(float a, float b) {
  u32 ua = __builtin_bit_cast(u32, a) + 0x8000u;
  u32 ub = __builtin_bit_cast(u32, b) + 0x8000u;
  return __builtin_amdgcn_perm(ub, ua, 0x07060302);  // {lo: a, hi: b}
}

// async global->LDS DMA, 16B per lane. LDS dest is wave-uniform base + lane*16
// (dest must be linear in lane order; global src is per-lane).
DEV void gl16(const u16* __restrict__ g, u16* l) {
  __builtin_amdgcn_global_load_lds((const __attribute__((address_space(1))) u32*)g,
                                   (__attribute__((address_space(3))) u32*)l, 16, 0, 0);
}

// ---- merged prep: x pack + W_qkv transpose + W_out transpose (one dispatch) ----
__global__ __launch_bounds__(256) void k_prep(const float* __restrict__ x, u16* __restrict__ Xb,
                                              const float* __restrict__ Wqkv, u16* __restrict__ WqkvT,
                                              const float* __restrict__ Wout, u16* __restrict__ WoutT) {
  __shared__ float t[32][33];
  const int bid = blockIdx.x;
  const int tid = threadIdx.x;
  if (bid < 4096) {  // pack x: 4096 blocks x 256 threads x 1 float4
    const int i = bid * 256 + tid;
    const float4 v = reinterpret_cast<const float4*>(x)[i];
    ushort4 o;
    o.x = f2bf(v.x); o.y = f2bf(v.y); o.z = f2bf(v.z); o.w = f2bf(v.w);
    reinterpret_cast<ushort4*>(Xb)[i] = o;
    return;
  }
  const float* in;
  u16* out;
  int R, C, bx, by;
  if (bid < 4096 + 3072) {  // W_qkv [1024][3072] -> [3072][1024]
    const int b = bid - 4096;
    in = Wqkv; out = WqkvT; R = 1024; C = 3072;
    bx = b % 96; by = b / 96;
  } else {  // W_out [1024][1024] -> [1024][1024]^T
    const int b = bid - 7168;
    in = Wout; out = WoutT; R = 1024; C = 1024;
    bx = b & 31; by = b >> 5;
  }
  const int tx = tid & 31, ty = tid >> 5;
  const int c0 = bx * 32, r0 = by * 32;
  for (int i = ty; i < 32; i += 8)
    t[i][tx] = in[(size_t)(r0 + i) * C + c0 + tx];
  __syncthreads();
  for (int i = ty; i < 32; i += 8)
    out[(size_t)(c0 + i) * R + r0 + tx] = f2bf(t[tx][i]);
}

// ---- 128x128 bf16 GEMM (QKV): dbuf gl_lds pipeline + LT overlay + XCD swizzle ----
__global__ __launch_bounds__(256, 5) void k_gemm0(const u16* __restrict__ A, const u16* __restrict__ Bt,
                                                  const float* __restrict__ bias, int M, int N, int K,
                                                  u16* __restrict__ Qb, u16* __restrict__ Kb,
                                                  u16* __restrict__ Vt) {
  constexpr int TN = 128, NJ = 4;
  constexpr int ASZ = 2 * 128 * 32 * 2;  // 16384
  __shared__ __align__(16) char smem[ASZ + 2 * TN * 32 * 2];  // 32768
  auto As = reinterpret_cast<u16(*)[128][32]>(smem);
  auto Bs = reinterpret_cast<u16(*)[TN][32]>(smem + ASZ);
  auto LT = reinterpret_cast<u16(*)[136]>(smem);  // epilogue-only overlay, 64x136x2 = 17408B
  const int tid = threadIdx.x;
  const int lane = tid & 63, wave = tid >> 6;
  const int l15 = lane & 15, quad = lane >> 4;
  // XCD swizzle: nwg = 24*32 = 768, chunk = 96 (4 M-rows of 24)
  const int bid0 = blockIdx.x + 24 * blockIdx.y;
  const int bid = (bid0 & 7) * 96 + (bid0 >> 3);
  const int m0 = (bid / 24) * 128, n0 = (bid % 24) * TN;
  const int wm = (wave >> 1) * 64, wn = (wave & 1) * (TN / 2);
  const int lr = lane >> 2;  // 0..15: row within a 16-row staging group
  const int lcs = ((((lane & 3) - (lane >> 3)) & 3)) * 8;   // inverse-swizzled source col
  const int sq = ((quad + (l15 >> 1)) & 3) * 8;             // swizzled read col

  f32x4 acc[4][NJ];
#pragma unroll
  for (int i = 0; i < 4; i++)
#pragma unroll
    for (int j = 0; j < NJ; j++) acc[i][j] = (f32x4){0.f, 0.f, 0.f, 0.f};

  const u16* Aw0 = &A[(size_t)(m0 + wave * 32 + lr) * K + lcs];
  const u16* Aw1 = &A[(size_t)(m0 + wave * 32 + 16 + lr) * K + lcs];
  const u16* Bw0 = &Bt[(size_t)(n0 + wave * 32 + lr) * K + lcs];
  const u16* Bw1 = &Bt[(size_t)(n0 + wave * 32 + 16 + lr) * K + lcs];

  gl16(Aw0, &As[0][wave * 32][0]);
  gl16(Aw1, &As[0][wave * 32 + 16][0]);
  gl16(Bw0, &Bs[0][wave * 32][0]);
  gl16(Bw1, &Bs[0][wave * 32 + 16][0]);

  int cur = 0;
#pragma unroll 2
  for (int kk = 0; kk < K; kk += 32, cur ^= 1) {
    __syncthreads();
    if (kk + 32 < K) {
      gl16(Aw0 + kk + 32, &As[cur ^ 1][wave * 32][0]);
      gl16(Aw1 + kk + 32, &As[cur ^ 1][wave * 32 + 16][0]);
      gl16(Bw0 + kk + 32, &Bs[cur ^ 1][wave * 32][0]);
      gl16(Bw1 + kk + 32, &Bs[cur ^ 1][wave * 32 + 16][0]);
    }
    bf16x8 af[4], bfv[NJ];
#pragma unroll
    for (int i = 0; i < 4; i++)
      af[i] = *reinterpret_cast<const bf16x8*>(&As[cur][wm + i * 16 + l15][sq]);
#pragma unroll
    for (int j = 0; j < NJ; j++)
      bfv[j] = *reinterpret_cast<const bf16x8*>(&Bs[cur][wn + j * 16 + l15][sq]);
#pragma unroll
    for (int i = 0; i < 4; i++)
#pragma unroll
      for (int j = 0; j < NJ; j++)
        acc[i][j] = __builtin_amdgcn_mfma_f32_16x16x32_bf16(af[i], bfv[j], acc[i][j], 0, 0, 0);
  }

  if (n0 >= 2048) {
    // ---- V blocks: LDS transpose (LT overlays As/Bs) -> coalesced stores along s ----
    const int b = m0 >> 11, sbase = m0 & 2047;
#pragma unroll
    for (int p = 0; p < 2; p++) {
      __syncthreads();
      if ((wave & 1) == p) {
#pragma unroll
        for (int j = 0; j < NJ; j++) {
          const int n = n0 + wn + j * 16 + l15;
          const float vb = bias[n];
#pragma unroll
          for (int i = 0; i < 4; i++) {
            uint2 pw;
            pw.x = pk2(acc[i][j][0] + vb, acc[i][j][1] + vb);
            pw.y = pk2(acc[i][j][2] + vb, acc[i][j][3] + vb);
            *reinterpret_cast<uint2*>(&LT[j * 16 + l15][wm + i * 16 + quad * 4]) = pw;
          }
        }
      }
      __syncthreads();
      const int h = ((n0 - 2048) >> 6) + p;
      const int bh = b * 16 + h;
      const int nl = tid >> 2, cc = (tid & 3) * 32;
      u16* dst = &Vt[((size_t)bh * 64 + nl) * S + sbase + cc];
#pragma unroll
      for (int k = 0; k < 4; k++)
        reinterpret_cast<uint4*>(dst)[k] = *reinterpret_cast<const uint4*>(&LT[nl][cc + k * 8]);
    }
  } else {
    // ---- Q/K blocks: direct stores (coalesced over l15) ----
#pragma unroll
    for (int i = 0; i < 4; i++) {
#pragma unroll
      for (int j = 0; j < NJ; j++) {
#pragma unroll
        for (int r = 0; r < 4; r++) {
          const int m = m0 + wm + i * 16 + quad * 4 + r;
          const int n = n0 + wn + j * 16 + l15;
          const float v = acc[i][j][r] + bias[n];
          const int h = (n >> 6) & 15, dh = n & 63;
          const int b = m >> 11, s = m & 2047;
          const int bh = b * 16 + h;
          if (n < 1024) Qb[((size_t)bh * S + s) * 64 + dh] = f2bfr(v * SCQ);
          else          Kb[((size_t)bh * S + s) * 64 + dh] = f2bfr(v);
        }
      }
    }
  }
}

// ---- out-proj GEMM: 128x64 tile, BK=64 + bijective XCD swizzle (512=8*64) ----
__global__ __launch_bounds__(256, 2) void k_gemm2(const u16* __restrict__ A, const u16* __restrict__ Bt,
                                                  const float* __restrict__ bias, float* __restrict__ outF) {
  constexpr int K = 1024, N = 1024;
  constexpr int ASZ = 2 * 128 * 64 * 2;  // 32768
  __shared__ __align__(16) char smem[ASZ + 2 * 64 * 64 * 2];  // 49152
  auto As = reinterpret_cast<u16(*)[128][64]>(smem);
  auto Bs = reinterpret_cast<u16(*)[64][64]>(smem + ASZ);
  const int tid = threadIdx.x;
  const int lane = tid & 63, wave = tid >> 6;
  const int l15 = lane & 15, quad = lane >> 4;
  // XCD swizzle: nwg = 16*32 = 512, chunk = 64
  const int bid0 = blockIdx.x + 16 * blockIdx.y;
  const int bid = (bid0 & 7) * 64 + (bid0 >> 3);
  const int m0 = (bid >> 4) * 128, n0 = (bid & 15) * 64;
  const int wm = (wave >> 1) * 64, wn = (wave & 1) * 32;
  const int srow = lane >> 3;                       // 0..7 row within 8-row chunk
  const int scol = ((lane & 7) ^ srow) * 8;         // inverse-swizzled source col

  f32x4 acc[4][2];
#pragma unroll
  for (int i = 0; i < 4; i++)
#pragma unroll
    for (int j = 0; j < 2; j++) acc[i][j] = (f32x4){0.f, 0.f, 0.f, 0.f};

  // staging pointers: A 16 chunks of 8 rows (4/wave), B 8 chunks (2/wave)
  const u16* Ap[4];
  const u16* Bp[2];
#pragma unroll
  for (int c = 0; c < 4; c++)
    Ap[c] = &A[(size_t)(m0 + (wave * 4 + c) * 8 + srow) * K + scol];
#pragma unroll
  for (int c = 0; c < 2; c++)
    Bp[c] = &Bt[(size_t)(n0 + (wave * 2 + c) * 8 + srow) * K + scol];

  // prologue: stage K-tile 0 into buf 0
#pragma unroll
  for (int c = 0; c < 4; c++) gl16(Ap[c], &As[0][(wave * 4 + c) * 8][0]);
#pragma unroll
  for (int c = 0; c < 2; c++) gl16(Bp[c], &Bs[0][(wave * 2 + c) * 8][0]);

  int cur = 0;
#pragma unroll 2
  for (int kk = 0; kk < K; kk += 64, cur ^= 1) {
    __syncthreads();  // buf[cur] staged; prev reads of buf[cur^1] done
    if (kk + 64 < K) {
#pragma unroll
      for (int c = 0; c < 4; c++) gl16(Ap[c] + kk + 64, &As[cur ^ 1][(wave * 4 + c) * 8][0]);
#pragma unroll
      for (int c = 0; c < 2; c++) gl16(Bp[c] + kk + 64, &Bs[cur ^ 1][(wave * 2 + c) * 8][0]);
    }
#pragma unroll
    for (int ks = 0; ks < 2; ks++) {
      const int sc = ((ks * 4 + quad) ^ (l15 & 7)) * 8;  // swizzled read col
      bf16x8 af[4], bfv[2];
#pragma unroll
      for (int i = 0; i < 4; i++)
        af[i] = *reinterpret_cast<const bf16x8*>(&As[cur][wm + i * 16 + l15][sc]);
#pragma unroll
      for (int j = 0; j < 2; j++)
        bfv[j] = *reinterpret_cast<const bf16x8*>(&Bs[cur][wn + j * 16 + l15][sc]);
#pragma unroll
      for (int i = 0; i < 4; i++)
#pragma unroll
        for (int j = 0; j < 2; j++)
          acc[i][j] = __builtin_amdgcn_mfma_f32_16x16x32_bf16(af[i], bfv[j], acc[i][j], 0, 0, 0);
    }
  }

#pragma unroll
  for (int i = 0; i < 4; i++)
#pragma unroll
    for (int j = 0; j < 2; j++)
#pragma unroll
      for (int r = 0; r < 4; r++) {
        const int m = m0 + wm + i * 16 + quad * 4 + r;
        const int n = n0 + wn + j * 16 + l15;
        outF[(size_t)m * N + n] = acc[i][j][r] + bias[n];
      }
}

// ---- flash attention: QBLK=128, 4 waves (R10 shape — QBLK=64 refuted in R12:
// K/V staging per FLOP doubled, 49.5->62us). NEW: double-buffered K/V LDS ->
// ONE barrier per key-iter (32 vs 64). Free: occupancy is grid-limited
// (512 blocks = 2/CU), so LDS 36.9->55.3KB costs nothing, and the global
// prefetch now has a full iteration in flight (vmcnt wait at ds_write free).
// Ordering: iter k writes buf[(k+1)&1], reads buf[k&1]; the single barrier at
// top of iter k orders iter k-1's reads of buf[(k+1)&1] before the writes.
// XCD swizzle (FETCH 69.7->12.3MB). T5 setprio. T12 in-register P (R9).
// Named uint4 prefetch scalars only — arrays spill to scratch (R6/R11).
__global__ __launch_bounds__(256, 2) void k_attn(const u16* __restrict__ Qb,
                                                 const u16* __restrict__ Kb,
                                                 const u16* __restrict__ Vt,
                                                 u16* __restrict__ attnB) {
  __shared__ u16 Ks[2][64][72];  // [buf][key][dh]       18.4KB
  __shared__ u16 Vs[2][64][72];  // [buf][dh][key_local] 18.4KB
  __shared__ u16 Pl[4][32][72];  // epilogue-only (O staging) 18.4KB
  const int tid = threadIdx.x;
  const int lane = tid & 63, wave = tid >> 6;
  const int l31 = lane & 31, hi = lane >> 5;
  // XCD swizzle: nwg = 512, chunk = 64 (4 bh of 16 q-blocks per XCD)
  const int bid0 = blockIdx.x + 16 * blockIdx.y;
  const int bid = (bid0 & 7) * 64 + (bid0 >> 3);
  const int bh = bid >> 4;
  const int q0 = (bid & 15) * 128;
  const u16* Qh = Qb + (size_t)bh * S * 64;
  const u16* Kh = Kb + (size_t)bh * S * 64;
  const u16* Vh = Vt + (size_t)bh * 64 * S;
  const int qrow = q0 + wave * 32 + l31;
  bf16x8 qf[4];  // Q (pre-scaled by SCQ) as B-operand: n = lane&31 = q
#pragma unroll
  for (int f = 0; f < 4; f++)
    qf[f] = *reinterpret_cast<const bf16x8*>(&Qh[(size_t)qrow * 64 + f * 16 + hi * 8]);

  const int r0 = tid >> 3, c0 = (tid & 7) * 8;  // staging: 8 lanes x 16B per 128B row

  float li = 0.f;
  f32x16 o0, o1;  // O d-tiles: d = dt*32 + (reg&3)+8*(reg>>2)+4*hi
#pragma unroll
  for (int r = 0; r < 16; r++) { o0[r] = 0.f; o1[r] = 0.f; }

  // tile 0 -> regs -> buf0 (no barrier needed: reads of buf0 come after iter0's barrier)
  uint4 pk0 = *reinterpret_cast<const uint4*>(&Kh[(size_t)r0 * 64 + c0]);
  uint4 pk1 = *reinterpret_cast<const uint4*>(&Kh[(size_t)(r0 + 32) * 64 + c0]);
  uint4 pv0 = *reinterpret_cast<const uint4*>(&Vh[(size_t)r0 * S + c0]);
  uint4 pv1 = *reinterpret_cast<const uint4*>(&Vh[(size_t)(r0 + 32) * S + c0]);
  *reinterpret_cast<uint4*>(&Ks[0][r0][c0]) = pk0;
  *reinterpret_cast<uint4*>(&Ks[0][r0 + 32][c0]) = pk1;
  *reinterpret_cast<uint4*>(&Vs[0][r0][c0]) = pv0;
  *reinterpret_cast<uint4*>(&Vs[0][r0 + 32][c0]) = pv1;
  // tile 1 -> regs
  {
    const u16* Kn = Kh + (size_t)64 * 64;
    pk0 = *reinterpret_cast<const uint4*>(&Kn[(size_t)r0 * 64 + c0]);
    pk1 = *reinterpret_cast<const uint4*>(&Kn[(size_t)(r0 + 32) * 64 + c0]);
    pv0 = *reinterpret_cast<const uint4*>(&Vh[(size_t)r0 * S + 64 + c0]);
    pv1 = *reinterpret_cast<const uint4*>(&Vh[(size_t)(r0 + 32) * S + 64 + c0]);
  }

  constexpr int NT = S / 64;  // 32
  for (int kb = 0; kb < NT; kb++) {
    const int cur = kb & 1, nxt = cur ^ 1;
    __syncthreads();  // buf[cur] complete; buf[nxt] free (prev reads done)
    if (kb + 1 < NT) {  // write tile kb+1 (regs) -> buf[nxt]
      *reinterpret_cast<uint4*>(&Ks[nxt][r0][c0]) = pk0;
      *reinterpret_cast<uint4*>(&Ks[nxt][r0 + 32][c0]) = pk1;
      *reinterpret_cast<uint4*>(&Vs[nxt][r0][c0]) = pv0;
      *reinterpret_cast<uint4*>(&Vs[nxt][r0 + 32][c0]) = pv1;
    }
    if (kb + 2 < NT) {  // issue tile kb+2 loads (land during next iteration)
      const u16* Kn = Kh + (size_t)(kb + 2) * 64 * 64;
      pk0 = *reinterpret_cast<const uint4*>(&Kn[(size_t)r0 * 64 + c0]);
      pk1 = *reinterpret_cast<const uint4*>(&Kn[(size_t)(r0 + 32) * 64 + c0]);
      pv0 = *reinterpret_cast<const uint4*>(&Vh[(size_t)r0 * S + (kb + 2) * 64 + c0]);
      pv1 = *reinterpret_cast<const uint4*>(&Vh[(size_t)(r0 + 32) * S + (kb + 2) * 64 + c0]);
    }
    // QK^T: 2 key-tiles x 4 k-steps (Q pre-scaled -> z is log2-domain score)
    f32x16 z[2];
    __builtin_amdgcn_s_setprio(1);
#pragma unroll
    for (int kt = 0; kt < 2; kt++) {
#pragma unroll
      for (int r = 0; r < 16; r++) z[kt][r] = 0.f;
#pragma unroll
      for (int f = 0; f < 4; f++) {
        const bf16x8 a = *reinterpret_cast<const bf16x8*>(&Ks[cur][kt * 32 + l31][f * 16 + hi * 8]);
        z[kt] = __builtin_amdgcn_mfma_f32_32x32x16_bf16(a, qf[f], z[kt], 0, 0, 0);
      }
    }
    __builtin_amdgcn_s_setprio(0);
    // p = exp2(z); accumulate denominator (4-way partials)
    float s0 = 0.f, s1 = 0.f, s2 = 0.f, s3 = 0.f;
#pragma unroll
    for (int kt = 0; kt < 2; kt++)
#pragma unroll
      for (int r = 0; r < 16; r++) {
        const float p = __builtin_amdgcn_exp2f(z[kt][r]);
        z[kt][r] = p;
        if ((r & 3) == 0) s0 += p; else if ((r & 3) == 1) s1 += p;
        else if ((r & 3) == 2) s2 += p; else s3 += p;
      }
    li += (s0 + s1) + (s2 + s3);
    // PV: A = V^T rows, B = P built in-register (pk2 + permlane32_swap)
    __builtin_amdgcn_s_setprio(1);
#pragma unroll
    for (int kt = 0; kt < 2; kt++) {
#pragma unroll
      for (int s = 0; s < 2; s++) {
        u32 w0 = pk2(z[kt][s * 8 + 0], z[kt][s * 8 + 1]);
        u32 w2 = pk2(z[kt][s * 8 + 4], z[kt][s * 8 + 5]);
        asm("v_permlane32_swap_b32 %0, %1" : "+v"(w0), "+v"(w2));
        u32 w1 = pk2(z[kt][s * 8 + 2], z[kt][s * 8 + 3]);
        u32 w3 = pk2(z[kt][s * 8 + 6], z[kt][s * 8 + 7]);
        asm("v_permlane32_swap_b32 %0, %1" : "+v"(w1), "+v"(w3));
        uint4 wv;
        wv.x = w0; wv.y = w1; wv.z = w2; wv.w = w3;
        const bf16x8 bp = __builtin_bit_cast(bf16x8, wv);
        const int f = kt * 2 + s;
        const bf16x8 av0 = *reinterpret_cast<const bf16x8*>(&Vs[cur][l31][f * 16 + hi * 8]);
        const bf16x8 av1 = *reinterpret_cast<const bf16x8*>(&Vs[cur][32 + l31][f * 16 + hi * 8]);
        o0 = __builtin_amdgcn_mfma_f32_32x32x16_bf16(av0, bp, o0, 0, 0, 0);
        o1 = __builtin_amdgcn_mfma_f32_32x32x16_bf16(av1, bp, o1, 0, 0, 0);
      }
    }
    __builtin_amdgcn_s_setprio(0);
  }
  li += __shfl_xor(li, 32);
  const float inv = 1.f / li;
  // O -> Pl[q][d] (wave-private), then coalesced store
#pragma unroll
  for (int dt = 0; dt < 2; dt++) {
    const f32x16& od = dt ? o1 : o0;
#pragma unroll
    for (int g = 0; g < 4; g++) {
      uint2 ow;
      ow.x = pk2(od[g * 4 + 0] * inv, od[g * 4 + 1] * inv);
      ow.y = pk2(od[g * 4 + 2] * inv, od[g * 4 + 3] * inv);
      *reinterpret_cast<uint2*>(&Pl[wave][l31][dt * 32 + g * 8 + hi * 4]) = ow;
    }
  }
  const int b = bh >> 4, h = bh & 15;
  const int mbase = b * S + q0 + wave * 32;
  const int qr = lane >> 1, ch = (lane & 1) * 32;
  u16* dst = &attnB[(size_t)(mbase + qr) * D + h * 64 + ch];
#pragma unroll
  for (int c = 0; c < 4; c++)
    reinterpret_cast<uint4*>(dst)[c] = *reinterpret_cast<const uint4*>(&Pl[wave][qr][ch + c * 8]);
}

extern "C" void kernel_launch(void* const* d_in, const int* in_sizes, int n_in,
                              void* d_out, int out_size, void* d_ws, size_t ws_size,
                              hipStream_t stream) {
  const float* x = (const float*)d_in[0];
  const float* Wqkv = (const float*)d_in[1];
  const float* bqkv = (const float*)d_in[2];
  const float* Wout = (const float*)d_in[3];
  const float* bout = (const float*)d_in[4];
  float* out = (float*)d_out;

  char* p = (char*)d_ws;
  u16* WoutT = (u16*)p; p += (size_t)1024 * 1024 * 2;     // 2MB  (live thru gemm2)
  u16* attnB = (u16*)p; p += (size_t)4096 * 1024 * 2;     // 8MB  (live thru gemm2)
  u16* Xb = (u16*)p;    p += (size_t)4096 * 1024 * 2;     // 8MB  (dead after gemm0)
  u16* WqkvT = (u16*)p; p += (size_t)3072 * 1024 * 2;     // 6MB  (dead after gemm0)
  u16* Vt = (u16*)p;    p += (size_t)32 * 64 * 2048 * 2;  // 8MB  (dead after attn)
  u16* Qb = (u16*)p;    p += (size_t)32 * 2048 * 64 * 2;  // 8MB  (dead after attn)
  u16* Kb = (u16*)p;    p += (size_t)32 * 2048 * 64 * 2;  // 8MB  (dead after attn)

  k_prep<<<4096 + 3072 + 1024, 256, 0, stream>>>(x, Xb, Wqkv, WqkvT, Wout, WoutT);
  k_gemm0<<<dim3(3072 / 128, 4096 / 128), 256, 0, stream>>>(
      Xb, WqkvT, bqkv, 4096, 3072, 1024, Qb, Kb, Vt);
  k_attn<<<dim3(2048 / 128, 32), 256, 0, stream>>>(Qb, Kb, Vt, attnB);
  k_gemm2<<<dim3(1024 / 64, 4096 / 128), 256, 0, stream>>>(attnB, WoutT, bout, out);
}

// Round 14
// 174.657 us; speedup vs baseline: 1.6367x; 1.0735x over previous
//
#include <hip/hip_runtime.h>
#include <hip/hip_bf16.h>

#define DEV __device__ __forceinline__

typedef __bf16 bf16x8 __attribute__((ext_vector_type(8)));
typedef float f32x4 __attribute__((ext_vector_type(4)));
typedef float f32x16 __attribute__((ext_vector_type(16)));
using u16 = unsigned short;
using u32 = unsigned int;

static constexpr int S = 2048;
static constexpr int D = 1024;
static constexpr float SCQ = 0.125f * 1.44269504088896340736f;  // 1/sqrt(64)*log2(e)

DEV u16 f2bf(float f) {  // RNE
  unsigned u = __builtin_bit_cast(unsigned, f);
  u += 0x7fffu + ((u >> 16) & 1u);
  return (u16)(u >> 16);
}
DEV u16 f2bfr(float f) {  // round-half-up (cheap)
  return (u16)((__builtin_bit_cast(u32, f) + 0x8000u) >> 16);
}
// two f32 -> packed bf16x2, round-half-up: 2 int adds + one v_perm
DEV u32 pk2(float a, float b) {
  u32 ua = __builtin_bit_cast(u32, a) + 0x8000u;
  u32 ub = __builtin_bit_cast(u32, b) + 0x8000u;
  return __builtin_amdgcn_perm(ub, ua, 0x07060302);  // {lo: a, hi: b}
}

// async global->LDS DMA, 16B per lane. LDS dest is wave-uniform base + lane*16
// (dest must be linear in lane order; global src is per-lane).
DEV void gl16(const u16* __restrict__ g, u16* l) {
  __builtin_amdgcn_global_load_lds((const __attribute__((address_space(1))) u32*)g,
                                   (__attribute__((address_space(3))) u32*)l, 16, 0, 0);
}

// ---- merged prep: x pack + W_qkv transpose + W_out transpose (one dispatch) ----
__global__ __launch_bounds__(256) void k_prep(const float* __restrict__ x, u16* __restrict__ Xb,
                                              const float* __restrict__ Wqkv, u16* __restrict__ WqkvT,
                                              const float* __restrict__ Wout, u16* __restrict__ WoutT) {
  __shared__ float t[32][33];
  const int bid = blockIdx.x;
  const int tid = threadIdx.x;
  if (bid < 4096) {  // pack x: 4096 blocks x 256 threads x 1 float4
    const int i = bid * 256 + tid;
    const float4 v = reinterpret_cast<const float4*>(x)[i];
    ushort4 o;
    o.x = f2bf(v.x); o.y = f2bf(v.y); o.z = f2bf(v.z); o.w = f2bf(v.w);
    reinterpret_cast<ushort4*>(Xb)[i] = o;
    return;
  }
  const float* in;
  u16* out;
  int R, C, bx, by;
  if (bid < 4096 + 3072) {  // W_qkv [1024][3072] -> [3072][1024]
    const int b = bid - 4096;
    in = Wqkv; out = WqkvT; R = 1024; C = 3072;
    bx = b % 96; by = b / 96;
  } else {  // W_out [1024][1024] -> [1024][1024]^T
    const int b = bid - 7168;
    in = Wout; out = WoutT; R = 1024; C = 1024;
    bx = b & 31; by = b >> 5;
  }
  const int tx = tid & 31, ty = tid >> 5;
  const int c0 = bx * 32, r0 = by * 32;
  for (int i = ty; i < 32; i += 8)
    t[i][tx] = in[(size_t)(r0 + i) * C + c0 + tx];
  __syncthreads();
  for (int i = ty; i < 32; i += 8)
    out[(size_t)(c0 + i) * R + r0 + tx] = f2bf(t[tx][i]);
}

// ---- 128x128 bf16 GEMM (QKV): T4 counted-vmcnt pipeline (triple-buffer,
// 2-tiles-ahead). __syncthreads() forced vmcnt(0) drain of the just-issued
// prefetch each K-step (R13 PMC: MfmaUtil 18%, VALUBusy 14% -> latency-bound).
// Now: raw s_barrier + per-wave s_waitcnt vmcnt(4) (tile k drained, tile k+1's
// 4 loads stay in flight across the barrier); tile k+2 issued post-barrier into
// the buf last read at iter k-1 (ordered by the execution barrier).
// sched_barrier(0) pins ds_read/gl16 issue below the barrier (rule #18).
// LDS 3x16KB = 48KB -> 3 blocks/CU (grid-bound at 3 anyway). LT overlay fits.
__global__ __launch_bounds__(256, 3) void k_gemm0(const u16* __restrict__ A, const u16* __restrict__ Bt,
                                                  const float* __restrict__ bias, int M, int N, int K,
                                                  u16* __restrict__ Qb, u16* __restrict__ Kb,
                                                  u16* __restrict__ Vt) {
  constexpr int TN = 128, NJ = 4;
  constexpr int BSZ = 128 * 32 * 2;  // 8192 per operand per buf
  __shared__ __align__(16) char smem[3 * 2 * BSZ];  // 49152
  auto As = reinterpret_cast<u16(*)[128][32]>(smem);
  auto Bs = reinterpret_cast<u16(*)[128][32]>(smem + 3 * BSZ);
  auto LT = reinterpret_cast<u16(*)[136]>(smem);  // epilogue-only overlay, 64x136x2 = 17408B
  const int tid = threadIdx.x;
  const int lane = tid & 63, wave = tid >> 6;
  const int l15 = lane & 15, quad = lane >> 4;
  // XCD swizzle: nwg = 24*32 = 768, chunk = 96 (4 M-rows of 24)
  const int bid0 = blockIdx.x + 24 * blockIdx.y;
  const int bid = (bid0 & 7) * 96 + (bid0 >> 3);
  const int m0 = (bid / 24) * 128, n0 = (bid % 24) * TN;
  const int wm = (wave >> 1) * 64, wn = (wave & 1) * (TN / 2);
  const int lr = lane >> 2;  // 0..15: row within a 16-row staging group
  const int lcs = ((((lane & 3) - (lane >> 3)) & 3)) * 8;   // inverse-swizzled source col
  const int sq = ((quad + (l15 >> 1)) & 3) * 8;             // swizzled read col

  f32x4 acc[4][NJ];
#pragma unroll
  for (int i = 0; i < 4; i++)
#pragma unroll
    for (int j = 0; j < NJ; j++) acc[i][j] = (f32x4){0.f, 0.f, 0.f, 0.f};

  const u16* Aw0 = &A[(size_t)(m0 + wave * 32 + lr) * K + lcs];
  const u16* Aw1 = &A[(size_t)(m0 + wave * 32 + 16 + lr) * K + lcs];
  const u16* Bw0 = &Bt[(size_t)(n0 + wave * 32 + lr) * K + lcs];
  const u16* Bw1 = &Bt[(size_t)(n0 + wave * 32 + 16 + lr) * K + lcs];

  // prologue: tiles 0,1 -> bufs 0,1 (4 gl16 each per wave)
  gl16(Aw0, &As[0][wave * 32][0]);
  gl16(Aw1, &As[0][wave * 32 + 16][0]);
  gl16(Bw0, &Bs[0][wave * 32][0]);
  gl16(Bw1, &Bs[0][wave * 32 + 16][0]);
  gl16(Aw0 + 32, &As[1][wave * 32][0]);
  gl16(Aw1 + 32, &As[1][wave * 32 + 16][0]);
  gl16(Bw0 + 32, &Bs[1][wave * 32][0]);
  gl16(Bw1 + 32, &Bs[1][wave * 32 + 16][0]);

  int cur = 0, nx2 = 2;
  for (int kk = 0; kk < K; kk += 32) {
    // vmcnt ledger: steady entry = 8 outstanding (tiles k, k+1). Wait ->4 keeps
    // tile k+1 in flight. Last iter: only tile k left (4) -> full drain.
    if (kk + 32 < K) asm volatile("s_waitcnt vmcnt(4)" ::: "memory");
    else             asm volatile("s_waitcnt vmcnt(0)" ::: "memory");
    __builtin_amdgcn_s_barrier();
    __builtin_amdgcn_sched_barrier(0);
    if (kk + 64 < K) {  // issue tile k+2 -> buf[nx2] (last read iter k-1)
      gl16(Aw0 + kk + 64, &As[nx2][wave * 32][0]);
      gl16(Aw1 + kk + 64, &As[nx2][wave * 32 + 16][0]);
      gl16(Bw0 + kk + 64, &Bs[nx2][wave * 32][0]);
      gl16(Bw1 + kk + 64, &Bs[nx2][wave * 32 + 16][0]);
    }
    bf16x8 af[4], bfv[NJ];
#pragma unroll
    for (int i = 0; i < 4; i++)
      af[i] = *reinterpret_cast<const bf16x8*>(&As[cur][wm + i * 16 + l15][sq]);
#pragma unroll
    for (int j = 0; j < NJ; j++)
      bfv[j] = *reinterpret_cast<const bf16x8*>(&Bs[cur][wn + j * 16 + l15][sq]);
#pragma unroll
    for (int i = 0; i < 4; i++)
#pragma unroll
      for (int j = 0; j < NJ; j++)
        acc[i][j] = __builtin_amdgcn_mfma_f32_16x16x32_bf16(af[i], bfv[j], acc[i][j], 0, 0, 0);
    cur = (cur == 2) ? 0 : cur + 1;
    nx2 = (nx2 == 2) ? 0 : nx2 + 1;
  }

  if (n0 >= 2048) {
    // ---- V blocks: LDS transpose (LT overlays staging bufs) -> stores along s ----
    const int b = m0 >> 11, sbase = m0 & 2047;
#pragma unroll
    for (int p = 0; p < 2; p++) {
      __syncthreads();
      if ((wave & 1) == p) {
#pragma unroll
        for (int j = 0; j < NJ; j++) {
          const int n = n0 + wn + j * 16 + l15;
          const float vb = bias[n];
#pragma unroll
          for (int i = 0; i < 4; i++) {
            uint2 pw;
            pw.x = pk2(acc[i][j][0] + vb, acc[i][j][1] + vb);
            pw.y = pk2(acc[i][j][2] + vb, acc[i][j][3] + vb);
            *reinterpret_cast<uint2*>(&LT[j * 16 + l15][wm + i * 16 + quad * 4]) = pw;
          }
        }
      }
      __syncthreads();
      const int h = ((n0 - 2048) >> 6) + p;
      const int bh = b * 16 + h;
      const int nl = tid >> 2, cc = (tid & 3) * 32;
      u16* dst = &Vt[((size_t)bh * 64 + nl) * S + sbase + cc];
#pragma unroll
      for (int k = 0; k < 4; k++)
        reinterpret_cast<uint4*>(dst)[k] = *reinterpret_cast<const uint4*>(&LT[nl][cc + k * 8]);
    }
  } else {
    // ---- Q/K blocks: direct stores (coalesced over l15) ----
#pragma unroll
    for (int i = 0; i < 4; i++) {
#pragma unroll
      for (int j = 0; j < NJ; j++) {
#pragma unroll
        for (int r = 0; r < 4; r++) {
          const int m = m0 + wm + i * 16 + quad * 4 + r;
          const int n = n0 + wn + j * 16 + l15;
          const float v = acc[i][j][r] + bias[n];
          const int h = (n >> 6) & 15, dh = n & 63;
          const int b = m >> 11, s = m & 2047;
          const int bh = b * 16 + h;
          if (n < 1024) Qb[((size_t)bh * S + s) * 64 + dh] = f2bfr(v * SCQ);
          else          Kb[((size_t)bh * S + s) * 64 + dh] = f2bfr(v);
        }
      }
    }
  }
}

// ---- out-proj GEMM: 128x64 tile, BK=64 + T4 counted-vmcnt triple-buffer
// (same transform as gemm0: 6 gl16/tile -> steady 12 outstanding, wait vmcnt(6)).
// LDS 3x24KB = 72KB -> 2 blocks/CU (grid-bound at 2 anyway).
__global__ __launch_bounds__(256, 2) void k_gemm2(const u16* __restrict__ A, const u16* __restrict__ Bt,
                                                  const float* __restrict__ bias, float* __restrict__ outF) {
  constexpr int K = 1024, N = 1024;
  constexpr int ABSZ = 128 * 64 * 2;  // 16384
  constexpr int BBSZ = 64 * 64 * 2;   // 8192
  __shared__ __align__(16) char smem[3 * (ABSZ + BBSZ)];  // 73728
  auto As = reinterpret_cast<u16(*)[128][64]>(smem);
  auto Bs = reinterpret_cast<u16(*)[64][64]>(smem + 3 * ABSZ);
  const int tid = threadIdx.x;
  const int lane = tid & 63, wave = tid >> 6;
  const int l15 = lane & 15, quad = lane >> 4;
  // XCD swizzle: nwg = 16*32 = 512, chunk = 64
  const int bid0 = blockIdx.x + 16 * blockIdx.y;
  const int bid = (bid0 & 7) * 64 + (bid0 >> 3);
  const int m0 = (bid >> 4) * 128, n0 = (bid & 15) * 64;
  const int wm = (wave >> 1) * 64, wn = (wave & 1) * 32;
  const int srow = lane >> 3;                       // 0..7 row within 8-row chunk
  const int scol = ((lane & 7) ^ srow) * 8;         // inverse-swizzled source col

  f32x4 acc[4][2];
#pragma unroll
  for (int i = 0; i < 4; i++)
#pragma unroll
    for (int j = 0; j < 2; j++) acc[i][j] = (f32x4){0.f, 0.f, 0.f, 0.f};

  // staging pointers: A 16 chunks of 8 rows (4/wave), B 8 chunks (2/wave)
  const u16* Ap[4];
  const u16* Bp[2];
#pragma unroll
  for (int c = 0; c < 4; c++)
    Ap[c] = &A[(size_t)(m0 + (wave * 4 + c) * 8 + srow) * K + scol];
#pragma unroll
  for (int c = 0; c < 2; c++)
    Bp[c] = &Bt[(size_t)(n0 + (wave * 2 + c) * 8 + srow) * K + scol];

  // prologue: tiles 0,1 -> bufs 0,1 (6 gl16 each per wave)
#pragma unroll
  for (int c = 0; c < 4; c++) gl16(Ap[c], &As[0][(wave * 4 + c) * 8][0]);
#pragma unroll
  for (int c = 0; c < 2; c++) gl16(Bp[c], &Bs[0][(wave * 2 + c) * 8][0]);
#pragma unroll
  for (int c = 0; c < 4; c++) gl16(Ap[c] + 64, &As[1][(wave * 4 + c) * 8][0]);
#pragma unroll
  for (int c = 0; c < 2; c++) gl16(Bp[c] + 64, &Bs[1][(wave * 2 + c) * 8][0]);

  int cur = 0, nx2 = 2;
  for (int kk = 0; kk < K; kk += 64) {
    if (kk + 64 < K) asm volatile("s_waitcnt vmcnt(6)" ::: "memory");
    else             asm volatile("s_waitcnt vmcnt(0)" ::: "memory");
    __builtin_amdgcn_s_barrier();
    __builtin_amdgcn_sched_barrier(0);
    if (kk + 128 < K) {  // issue tile k+2 -> buf[nx2]
#pragma unroll
      for (int c = 0; c < 4; c++) gl16(Ap[c] + kk + 128, &As[nx2][(wave * 4 + c) * 8][0]);
#pragma unroll
      for (int c = 0; c < 2; c++) gl16(Bp[c] + kk + 128, &Bs[nx2][(wave * 2 + c) * 8][0]);
    }
#pragma unroll
    for (int ks = 0; ks < 2; ks++) {
      const int sc = ((ks * 4 + quad) ^ (l15 & 7)) * 8;  // swizzled read col
      bf16x8 af[4], bfv[2];
#pragma unroll
      for (int i = 0; i < 4; i++)
        af[i] = *reinterpret_cast<const bf16x8*>(&As[cur][wm + i * 16 + l15][sc]);
#pragma unroll
      for (int j = 0; j < 2; j++)
        bfv[j] = *reinterpret_cast<const bf16x8*>(&Bs[cur][wn + j * 16 + l15][sc]);
#pragma unroll
      for (int i = 0; i < 4; i++)
#pragma unroll
        for (int j = 0; j < 2; j++)
          acc[i][j] = __builtin_amdgcn_mfma_f32_16x16x32_bf16(af[i], bfv[j], acc[i][j], 0, 0, 0);
    }
    cur = (cur == 2) ? 0 : cur + 1;
    nx2 = (nx2 == 2) ? 0 : nx2 + 1;
  }

#pragma unroll
  for (int i = 0; i < 4; i++)
#pragma unroll
    for (int j = 0; j < 2; j++)
#pragma unroll
      for (int r = 0; r < 4; r++) {
        const int m = m0 + wm + i * 16 + quad * 4 + r;
        const int n = n0 + wn + j * 16 + l15;
        outF[(size_t)m * N + n] = acc[i][j][r] + bias[n];
      }
}

// ---- flash attention: QBLK=128, 4 waves, dbuf K/V (one barrier/key-iter).
// XCD swizzle (FETCH 69.7->12.3MB). T5 setprio. T12 in-register P (R9).
// Named uint4 prefetch scalars only — arrays spill to scratch (R6/R11).
__global__ __launch_bounds__(256, 2) void k_attn(const u16* __restrict__ Qb,
                                                 const u16* __restrict__ Kb,
                                                 const u16* __restrict__ Vt,
                                                 u16* __restrict__ attnB) {
  __shared__ u16 Ks[2][64][72];  // [buf][key][dh]       18.4KB
  __shared__ u16 Vs[2][64][72];  // [buf][dh][key_local] 18.4KB
  __shared__ u16 Pl[4][32][72];  // epilogue-only (O staging) 18.4KB
  const int tid = threadIdx.x;
  const int lane = tid & 63, wave = tid >> 6;
  const int l31 = lane & 31, hi = lane >> 5;
  // XCD swizzle: nwg = 512, chunk = 64 (4 bh of 16 q-blocks per XCD)
  const int bid0 = blockIdx.x + 16 * blockIdx.y;
  const int bid = (bid0 & 7) * 64 + (bid0 >> 3);
  const int bh = bid >> 4;
  const int q0 = (bid & 15) * 128;
  const u16* Qh = Qb + (size_t)bh * S * 64;
  const u16* Kh = Kb + (size_t)bh * S * 64;
  const u16* Vh = Vt + (size_t)bh * 64 * S;
  const int qrow = q0 + wave * 32 + l31;
  bf16x8 qf[4];  // Q (pre-scaled by SCQ) as B-operand: n = lane&31 = q
#pragma unroll
  for (int f = 0; f < 4; f++)
    qf[f] = *reinterpret_cast<const bf16x8*>(&Qh[(size_t)qrow * 64 + f * 16 + hi * 8]);

  const int r0 = tid >> 3, c0 = (tid & 7) * 8;  // staging: 8 lanes x 16B per 128B row

  float li = 0.f;
  f32x16 o0, o1;  // O d-tiles: d = dt*32 + (reg&3)+8*(reg>>2)+4*hi
#pragma unroll
  for (int r = 0; r < 16; r++) { o0[r] = 0.f; o1[r] = 0.f; }

  // tile 0 -> regs -> buf0
  uint4 pk0 = *reinterpret_cast<const uint4*>(&Kh[(size_t)r0 * 64 + c0]);
  uint4 pk1 = *reinterpret_cast<const uint4*>(&Kh[(size_t)(r0 + 32) * 64 + c0]);
  uint4 pv0 = *reinterpret_cast<const uint4*>(&Vh[(size_t)r0 * S + c0]);
  uint4 pv1 = *reinterpret_cast<const uint4*>(&Vh[(size_t)(r0 + 32) * S + c0]);
  *reinterpret_cast<uint4*>(&Ks[0][r0][c0]) = pk0;
  *reinterpret_cast<uint4*>(&Ks[0][r0 + 32][c0]) = pk1;
  *reinterpret_cast<uint4*>(&Vs[0][r0][c0]) = pv0;
  *reinterpret_cast<uint4*>(&Vs[0][r0 + 32][c0]) = pv1;
  // tile 1 -> regs
  {
    const u16* Kn = Kh + (size_t)64 * 64;
    pk0 = *reinterpret_cast<const uint4*>(&Kn[(size_t)r0 * 64 + c0]);
    pk1 = *reinterpret_cast<const uint4*>(&Kn[(size_t)(r0 + 32) * 64 + c0]);
    pv0 = *reinterpret_cast<const uint4*>(&Vh[(size_t)r0 * S + 64 + c0]);
    pv1 = *reinterpret_cast<const uint4*>(&Vh[(size_t)(r0 + 32) * S + 64 + c0]);
  }

  constexpr int NT = S / 64;  // 32
  for (int kb = 0; kb < NT; kb++) {
    const int cur = kb & 1, nxt = cur ^ 1;
    __syncthreads();  // buf[cur] complete; buf[nxt] free (prev reads done)
    if (kb + 1 < NT) {  // write tile kb+1 (regs) -> buf[nxt]
      *reinterpret_cast<uint4*>(&Ks[nxt][r0][c0]) = pk0;
      *reinterpret_cast<uint4*>(&Ks[nxt][r0 + 32][c0]) = pk1;
      *reinterpret_cast<uint4*>(&Vs[nxt][r0][c0]) = pv0;
      *reinterpret_cast<uint4*>(&Vs[nxt][r0 + 32][c0]) = pv1;
    }
    if (kb + 2 < NT) {  // issue tile kb+2 loads (land during next iteration)
      const u16* Kn = Kh + (size_t)(kb + 2) * 64 * 64;
      pk0 = *reinterpret_cast<const uint4*>(&Kn[(size_t)r0 * 64 + c0]);
      pk1 = *reinterpret_cast<const uint4*>(&Kn[(size_t)(r0 + 32) * 64 + c0]);
      pv0 = *reinterpret_cast<const uint4*>(&Vh[(size_t)r0 * S + (kb + 2) * 64 + c0]);
      pv1 = *reinterpret_cast<const uint4*>(&Vh[(size_t)(r0 + 32) * S + (kb + 2) * 64 + c0]);
    }
    // QK^T: 2 key-tiles x 4 k-steps (Q pre-scaled -> z is log2-domain score)
    f32x16 z[2];
    __builtin_amdgcn_s_setprio(1);
#pragma unroll
    for (int kt = 0; kt < 2; kt++) {
#pragma unroll
      for (int r = 0; r < 16; r++) z[kt][r] = 0.f;
#pragma unroll
      for (int f = 0; f < 4; f++) {
        const bf16x8 a = *reinterpret_cast<const bf16x8*>(&Ks[cur][kt * 32 + l31][f * 16 + hi * 8]);
        z[kt] = __builtin_amdgcn_mfma_f32_32x32x16_bf16(a, qf[f], z[kt], 0, 0, 0);
      }
    }
    __builtin_amdgcn_s_setprio(0);
    // p = exp2(z); accumulate denominator (4-way partials)
    float s0 = 0.f, s1 = 0.f, s2 = 0.f, s3 = 0.f;
#pragma unroll
    for (int kt = 0; kt < 2; kt++)
#pragma unroll
      for (int r = 0; r < 16; r++) {
        const float p = __builtin_amdgcn_exp2f(z[kt][r]);
        z[kt][r] = p;
        if ((r & 3) == 0) s0 += p; else if ((r & 3) == 1) s1 += p;
        else if ((r & 3) == 2) s2 += p; else s3 += p;
      }
    li += (s0 + s1) + (s2 + s3);
    // PV: A = V^T rows, B = P built in-register (pk2 + permlane32_swap)
    __builtin_amdgcn_s_setprio(1);
#pragma unroll
    for (int kt = 0; kt < 2; kt++) {
#pragma unroll
      for (int s = 0; s < 2; s++) {
        u32 w0 = pk2(z[kt][s * 8 + 0], z[kt][s * 8 + 1]);
        u32 w2 = pk2(z[kt][s * 8 + 4], z[kt][s * 8 + 5]);
        asm("v_permlane32_swap_b32 %0, %1" : "+v"(w0), "+v"(w2));
        u32 w1 = pk2(z[kt][s * 8 + 2], z[kt][s * 8 + 3]);
        u32 w3 = pk2(z[kt][s * 8 + 6], z[kt][s * 8 + 7]);
        asm("v_permlane32_swap_b32 %0, %1" : "+v"(w1), "+v"(w3));
        uint4 wv;
        wv.x = w0; wv.y = w1; wv.z = w2; wv.w = w3;
        const bf16x8 bp = __builtin_bit_cast(bf16x8, wv);
        const int f = kt * 2 + s;
        const bf16x8 av0 = *reinterpret_cast<const bf16x8*>(&Vs[cur][l31][f * 16 + hi * 8]);
        const bf16x8 av1 = *reinterpret_cast<const bf16x8*>(&Vs[cur][32 + l31][f * 16 + hi * 8]);
        o0 = __builtin_amdgcn_mfma_f32_32x32x16_bf16(av0, bp, o0, 0, 0, 0);
        o1 = __builtin_amdgcn_mfma_f32_32x32x16_bf16(av1, bp, o1, 0, 0, 0);
      }
    }
    __builtin_amdgcn_s_setprio(0);
  }
  li += __shfl_xor(li, 32);
  const float inv = 1.f / li;
  // O -> Pl[q][d] (wave-private), then coalesced store
#pragma unroll
  for (int dt = 0; dt < 2; dt++) {
    const f32x16& od = dt ? o1 : o0;
#pragma unroll
    for (int g = 0; g < 4; g++) {
      uint2 ow;
      ow.x = pk2(od[g * 4 + 0] * inv, od[g * 4 + 1] * inv);
      ow.y = pk2(od[g * 4 + 2] * inv, od[g * 4 + 3] * inv);
      *reinterpret_cast<uint2*>(&Pl[wave][l31][dt * 32 + g * 8 + hi * 4]) = ow;
    }
  }
  const int b = bh >> 4, h = bh & 15;
  const int mbase = b * S + q0 + wave * 32;
  const int qr = lane >> 1, ch = (lane & 1) * 32;
  u16* dst = &attnB[(size_t)(mbase + qr) * D + h * 64 + ch];
#pragma unroll
  for (int c = 0; c < 4; c++)
    reinterpret_cast<uint4*>(dst)[c] = *reinterpret_cast<const uint4*>(&Pl[wave][qr][ch + c * 8]);
}

extern "C" void kernel_launch(void* const* d_in, const int* in_sizes, int n_in,
                              void* d_out, int out_size, void* d_ws, size_t ws_size,
                              hipStream_t stream) {
  const float* x = (const float*)d_in[0];
  const float* Wqkv = (const float*)d_in[1];
  const float* bqkv = (const float*)d_in[2];
  const float* Wout = (const float*)d_in[3];
  const float* bout = (const float*)d_in[4];
  float* out = (float*)d_out;

  char* p = (char*)d_ws;
  u16* WoutT = (u16*)p; p += (size_t)1024 * 1024 * 2;     // 2MB  (live thru gemm2)
  u16* attnB = (u16*)p; p += (size_t)4096 * 1024 * 2;     // 8MB  (live thru gemm2)
  u16* Xb = (u16*)p;    p += (size_t)4096 * 1024 * 2;     // 8MB  (dead after gemm0)
  u16* WqkvT = (u16*)p; p += (size_t)3072 * 1024 * 2;     // 6MB  (dead after gemm0)
  u16* Vt = (u16*)p;    p += (size_t)32 * 64 * 2048 * 2;  // 8MB  (dead after attn)
  u16* Qb = (u16*)p;    p += (size_t)32 * 2048 * 64 * 2;  // 8MB  (dead after attn)
  u16* Kb = (u16*)p;    p += (size_t)32 * 2048 * 64 * 2;  // 8MB  (dead after attn)

  k_prep<<<4096 + 3072 + 1024, 256, 0, stream>>>(x, Xb, Wqkv, WqkvT, Wout, WoutT);
  k_gemm0<<<dim3(3072 / 128, 4096 / 128), 256, 0, stream>>>(
      Xb, WqkvT, bqkv, 4096, 3072, 1024, Qb, Kb, Vt);
  k_attn<<<dim3(2048 / 128, 32), 256, 0, stream>>>(Qb, Kb, Vt, attnB);
  k_gemm2<<<dim3(1024 / 64, 4096 / 128), 256, 0, stream>>>(attnB, WoutT, bout, out);
}

// Round 15
// 172.838 us; speedup vs baseline: 1.6540x; 1.0105x over previous
//
#include <hip/hip_runtime.h>
#include <hip/hip_bf16.h>

#define DEV __device__ __forceinline__

typedef __bf16 bf16x8 __attribute__((ext_vector_type(8)));
typedef float f32x4 __attribute__((ext_vector_type(4)));
typedef float f32x16 __attribute__((ext_vector_type(16)));
using u16 = unsigned short;
using u32 = unsigned int;

static constexpr int S = 2048;
static constexpr int D = 1024;
static constexpr float SCQ = 0.125f * 1.44269504088896340736f;  // 1/sqrt(64)*log2(e)

DEV u16 f2bf(float f) {  // RNE
  unsigned u = __builtin_bit_cast(unsigned, f);
  u += 0x7fffu + ((u >> 16) & 1u);
  return (u16)(u >> 16);
}
DEV u16 f2bfr(float f) {  // round-half-up (cheap)
  return (u16)((__builtin_bit_cast(u32, f) + 0x8000u) >> 16);
}
// two f32 -> packed bf16x2, round-half-up: 2 int adds + one v_perm
DEV u32 pk2(float a, float b) {
  u32 ua = __builtin_bit_cast(u32, a) + 0x8000u;
  u32 ub = __builtin_bit_cast(u32, b) + 0x8000u;
  return __builtin_amdgcn_perm(ub, ua, 0x07060302);  // {lo: a, hi: b}
}

// async global->LDS DMA, 16B per lane. LDS dest is wave-uniform base + lane*16
// (dest must be linear in lane order; global src is per-lane).
DEV void gl16(const u16* __restrict__ g, u16* l) {
  __builtin_amdgcn_global_load_lds((const __attribute__((address_space(1))) u32*)g,
                                   (__attribute__((address_space(3))) u32*)l, 16, 0, 0);
}

// ---- merged prep: x pack + W_qkv transpose + W_out transpose (one dispatch) ----
__global__ __launch_bounds__(256) void k_prep(const float* __restrict__ x, u16* __restrict__ Xb,
                                              const float* __restrict__ Wqkv, u16* __restrict__ WqkvT,
                                              const float* __restrict__ Wout, u16* __restrict__ WoutT) {
  __shared__ float t[32][33];
  const int bid = blockIdx.x;
  const int tid = threadIdx.x;
  if (bid < 4096) {  // pack x: 4096 blocks x 256 threads x 1 float4
    const int i = bid * 256 + tid;
    const float4 v = reinterpret_cast<const float4*>(x)[i];
    ushort4 o;
    o.x = f2bf(v.x); o.y = f2bf(v.y); o.z = f2bf(v.z); o.w = f2bf(v.w);
    reinterpret_cast<ushort4*>(Xb)[i] = o;
    return;
  }
  const float* in;
  u16* out;
  int R, C, bx, by;
  if (bid < 4096 + 3072) {  // W_qkv [1024][3072] -> [3072][1024]
    const int b = bid - 4096;
    in = Wqkv; out = WqkvT; R = 1024; C = 3072;
    bx = b % 96; by = b / 96;
  } else {  // W_out [1024][1024] -> [1024][1024]^T
    const int b = bid - 7168;
    in = Wout; out = WoutT; R = 1024; C = 1024;
    bx = b & 31; by = b >> 5;
  }
  const int tx = tid & 31, ty = tid >> 5;
  const int c0 = bx * 32, r0 = by * 32;
  for (int i = ty; i < 32; i += 8)
    t[i][tx] = in[(size_t)(r0 + i) * C + c0 + tx];
  __syncthreads();
  for (int i = ty; i < 32; i += 8)
    out[(size_t)(c0 + i) * R + r0 + tx] = f2bf(t[tx][i]);
}

// ---- 128x128 bf16 GEMM (QKV): T4 counted-vmcnt pipeline (triple-buffer,
// 2-tiles-ahead). R14: 54.0 -> <49 us. ----
__global__ __launch_bounds__(256, 3) void k_gemm0(const u16* __restrict__ A, const u16* __restrict__ Bt,
                                                  const float* __restrict__ bias, int M, int N, int K,
                                                  u16* __restrict__ Qb, u16* __restrict__ Kb,
                                                  u16* __restrict__ Vt) {
  constexpr int TN = 128, NJ = 4;
  constexpr int BSZ = 128 * 32 * 2;  // 8192 per operand per buf
  __shared__ __align__(16) char smem[3 * 2 * BSZ];  // 49152
  auto As = reinterpret_cast<u16(*)[128][32]>(smem);
  auto Bs = reinterpret_cast<u16(*)[128][32]>(smem + 3 * BSZ);
  auto LT = reinterpret_cast<u16(*)[136]>(smem);  // epilogue-only overlay, 64x136x2 = 17408B
  const int tid = threadIdx.x;
  const int lane = tid & 63, wave = tid >> 6;
  const int l15 = lane & 15, quad = lane >> 4;
  // XCD swizzle: nwg = 24*32 = 768, chunk = 96 (4 M-rows of 24)
  const int bid0 = blockIdx.x + 24 * blockIdx.y;
  const int bid = (bid0 & 7) * 96 + (bid0 >> 3);
  const int m0 = (bid / 24) * 128, n0 = (bid % 24) * TN;
  const int wm = (wave >> 1) * 64, wn = (wave & 1) * (TN / 2);
  const int lr = lane >> 2;  // 0..15: row within a 16-row staging group
  const int lcs = ((((lane & 3) - (lane >> 3)) & 3)) * 8;   // inverse-swizzled source col
  const int sq = ((quad + (l15 >> 1)) & 3) * 8;             // swizzled read col

  f32x4 acc[4][NJ];
#pragma unroll
  for (int i = 0; i < 4; i++)
#pragma unroll
    for (int j = 0; j < NJ; j++) acc[i][j] = (f32x4){0.f, 0.f, 0.f, 0.f};

  const u16* Aw0 = &A[(size_t)(m0 + wave * 32 + lr) * K + lcs];
  const u16* Aw1 = &A[(size_t)(m0 + wave * 32 + 16 + lr) * K + lcs];
  const u16* Bw0 = &Bt[(size_t)(n0 + wave * 32 + lr) * K + lcs];
  const u16* Bw1 = &Bt[(size_t)(n0 + wave * 32 + 16 + lr) * K + lcs];

  // prologue: tiles 0,1 -> bufs 0,1 (4 gl16 each per wave)
  gl16(Aw0, &As[0][wave * 32][0]);
  gl16(Aw1, &As[0][wave * 32 + 16][0]);
  gl16(Bw0, &Bs[0][wave * 32][0]);
  gl16(Bw1, &Bs[0][wave * 32 + 16][0]);
  gl16(Aw0 + 32, &As[1][wave * 32][0]);
  gl16(Aw1 + 32, &As[1][wave * 32 + 16][0]);
  gl16(Bw0 + 32, &Bs[1][wave * 32][0]);
  gl16(Bw1 + 32, &Bs[1][wave * 32 + 16][0]);

  int cur = 0, nx2 = 2;
  for (int kk = 0; kk < K; kk += 32) {
    // vmcnt ledger: steady entry = 8 outstanding (tiles k, k+1). Wait ->4 keeps
    // tile k+1 in flight. Last iter: only tile k left (4) -> full drain.
    if (kk + 32 < K) asm volatile("s_waitcnt vmcnt(4)" ::: "memory");
    else             asm volatile("s_waitcnt vmcnt(0)" ::: "memory");
    __builtin_amdgcn_s_barrier();
    __builtin_amdgcn_sched_barrier(0);
    if (kk + 64 < K) {  // issue tile k+2 -> buf[nx2] (last read iter k-1)
      gl16(Aw0 + kk + 64, &As[nx2][wave * 32][0]);
      gl16(Aw1 + kk + 64, &As[nx2][wave * 32 + 16][0]);
      gl16(Bw0 + kk + 64, &Bs[nx2][wave * 32][0]);
      gl16(Bw1 + kk + 64, &Bs[nx2][wave * 32 + 16][0]);
    }
    bf16x8 af[4], bfv[NJ];
#pragma unroll
    for (int i = 0; i < 4; i++)
      af[i] = *reinterpret_cast<const bf16x8*>(&As[cur][wm + i * 16 + l15][sq]);
#pragma unroll
    for (int j = 0; j < NJ; j++)
      bfv[j] = *reinterpret_cast<const bf16x8*>(&Bs[cur][wn + j * 16 + l15][sq]);
#pragma unroll
    for (int i = 0; i < 4; i++)
#pragma unroll
      for (int j = 0; j < NJ; j++)
        acc[i][j] = __builtin_amdgcn_mfma_f32_16x16x32_bf16(af[i], bfv[j], acc[i][j], 0, 0, 0);
    cur = (cur == 2) ? 0 : cur + 1;
    nx2 = (nx2 == 2) ? 0 : nx2 + 1;
  }

  if (n0 >= 2048) {
    // ---- V blocks: LDS transpose (LT overlays staging bufs) -> stores along s ----
    const int b = m0 >> 11, sbase = m0 & 2047;
#pragma unroll
    for (int p = 0; p < 2; p++) {
      __syncthreads();
      if ((wave & 1) == p) {
#pragma unroll
        for (int j = 0; j < NJ; j++) {
          const int n = n0 + wn + j * 16 + l15;
          const float vb = bias[n];
#pragma unroll
          for (int i = 0; i < 4; i++) {
            uint2 pw;
            pw.x = pk2(acc[i][j][0] + vb, acc[i][j][1] + vb);
            pw.y = pk2(acc[i][j][2] + vb, acc[i][j][3] + vb);
            *reinterpret_cast<uint2*>(&LT[j * 16 + l15][wm + i * 16 + quad * 4]) = pw;
          }
        }
      }
      __syncthreads();
      const int h = ((n0 - 2048) >> 6) + p;
      const int bh = b * 16 + h;
      const int nl = tid >> 2, cc = (tid & 3) * 32;
      u16* dst = &Vt[((size_t)bh * 64 + nl) * S + sbase + cc];
#pragma unroll
      for (int k = 0; k < 4; k++)
        reinterpret_cast<uint4*>(dst)[k] = *reinterpret_cast<const uint4*>(&LT[nl][cc + k * 8]);
    }
  } else {
    // ---- Q/K blocks: direct stores (coalesced over l15) ----
#pragma unroll
    for (int i = 0; i < 4; i++) {
#pragma unroll
      for (int j = 0; j < NJ; j++) {
#pragma unroll
        for (int r = 0; r < 4; r++) {
          const int m = m0 + wm + i * 16 + quad * 4 + r;
          const int n = n0 + wn + j * 16 + l15;
          const float v = acc[i][j][r] + bias[n];
          const int h = (n >> 6) & 15, dh = n & 63;
          const int b = m >> 11, s = m & 2047;
          const int bh = b * 16 + h;
          if (n < 1024) Qb[((size_t)bh * S + s) * 64 + dh] = f2bfr(v * SCQ);
          else          Kb[((size_t)bh * S + s) * 64 + dh] = f2bfr(v);
        }
      }
    }
  }
}

// ---- out-proj GEMM: 128x64 tile, BK=64 + T4 counted-vmcnt triple-buffer ----
__global__ __launch_bounds__(256, 2) void k_gemm2(const u16* __restrict__ A, const u16* __restrict__ Bt,
                                                  const float* __restrict__ bias, float* __restrict__ outF) {
  constexpr int K = 1024, N = 1024;
  constexpr int ABSZ = 128 * 64 * 2;  // 16384
  constexpr int BBSZ = 64 * 64 * 2;   // 8192
  __shared__ __align__(16) char smem[3 * (ABSZ + BBSZ)];  // 73728
  auto As = reinterpret_cast<u16(*)[128][64]>(smem);
  auto Bs = reinterpret_cast<u16(*)[64][64]>(smem + 3 * ABSZ);
  const int tid = threadIdx.x;
  const int lane = tid & 63, wave = tid >> 6;
  const int l15 = lane & 15, quad = lane >> 4;
  // XCD swizzle: nwg = 16*32 = 512, chunk = 64
  const int bid0 = blockIdx.x + 16 * blockIdx.y;
  const int bid = (bid0 & 7) * 64 + (bid0 >> 3);
  const int m0 = (bid >> 4) * 128, n0 = (bid & 15) * 64;
  const int wm = (wave >> 1) * 64, wn = (wave & 1) * 32;
  const int srow = lane >> 3;                       // 0..7 row within 8-row chunk
  const int scol = ((lane & 7) ^ srow) * 8;         // inverse-swizzled source col

  f32x4 acc[4][2];
#pragma unroll
  for (int i = 0; i < 4; i++)
#pragma unroll
    for (int j = 0; j < 2; j++) acc[i][j] = (f32x4){0.f, 0.f, 0.f, 0.f};

  // staging pointers: A 16 chunks of 8 rows (4/wave), B 8 chunks (2/wave)
  const u16* Ap[4];
  const u16* Bp[2];
#pragma unroll
  for (int c = 0; c < 4; c++)
    Ap[c] = &A[(size_t)(m0 + (wave * 4 + c) * 8 + srow) * K + scol];
#pragma unroll
  for (int c = 0; c < 2; c++)
    Bp[c] = &Bt[(size_t)(n0 + (wave * 2 + c) * 8 + srow) * K + scol];

  // prologue: tiles 0,1 -> bufs 0,1 (6 gl16 each per wave)
#pragma unroll
  for (int c = 0; c < 4; c++) gl16(Ap[c], &As[0][(wave * 4 + c) * 8][0]);
#pragma unroll
  for (int c = 0; c < 2; c++) gl16(Bp[c], &Bs[0][(wave * 2 + c) * 8][0]);
#pragma unroll
  for (int c = 0; c < 4; c++) gl16(Ap[c] + 64, &As[1][(wave * 4 + c) * 8][0]);
#pragma unroll
  for (int c = 0; c < 2; c++) gl16(Bp[c] + 64, &Bs[1][(wave * 2 + c) * 8][0]);

  int cur = 0, nx2 = 2;
  for (int kk = 0; kk < K; kk += 64) {
    if (kk + 64 < K) asm volatile("s_waitcnt vmcnt(6)" ::: "memory");
    else             asm volatile("s_waitcnt vmcnt(0)" ::: "memory");
    __builtin_amdgcn_s_barrier();
    __builtin_amdgcn_sched_barrier(0);
    if (kk + 128 < K) {  // issue tile k+2 -> buf[nx2]
#pragma unroll
      for (int c = 0; c < 4; c++) gl16(Ap[c] + kk + 128, &As[nx2][(wave * 4 + c) * 8][0]);
#pragma unroll
      for (int c = 0; c < 2; c++) gl16(Bp[c] + kk + 128, &Bs[nx2][(wave * 2 + c) * 8][0]);
    }
#pragma unroll
    for (int ks = 0; ks < 2; ks++) {
      const int sc = ((ks * 4 + quad) ^ (l15 & 7)) * 8;  // swizzled read col
      bf16x8 af[4], bfv[2];
#pragma unroll
      for (int i = 0; i < 4; i++)
        af[i] = *reinterpret_cast<const bf16x8*>(&As[cur][wm + i * 16 + l15][sc]);
#pragma unroll
      for (int j = 0; j < 2; j++)
        bfv[j] = *reinterpret_cast<const bf16x8*>(&Bs[cur][wn + j * 16 + l15][sc]);
#pragma unroll
      for (int i = 0; i < 4; i++)
#pragma unroll
        for (int j = 0; j < 2; j++)
          acc[i][j] = __builtin_amdgcn_mfma_f32_16x16x32_bf16(af[i], bfv[j], acc[i][j], 0, 0, 0);
    }
    cur = (cur == 2) ? 0 : cur + 1;
    nx2 = (nx2 == 2) ? 0 : nx2 + 1;
  }

#pragma unroll
  for (int i = 0; i < 4; i++)
#pragma unroll
    for (int j = 0; j < 2; j++)
#pragma unroll
      for (int r = 0; r < 4; r++) {
        const int m = m0 + wm + i * 16 + quad * 4 + r;
        const int n = n0 + wn + j * 16 + l15;
        outF[(size_t)m * N + n] = acc[i][j][r] + bias[n];
      }
}

// ---- attn helpers: produce (QK) and consume (softmax+PV) — inlined, all
// register state passed by reference (named f32x16s; arrays spill, R6/R11) ----
DEV void qk_produce(f32x16& z0, f32x16& z1, const u16 (*Ksb)[72],
                    const bf16x8* qf, int l31, int hi) {
#pragma unroll
  for (int r = 0; r < 16; r++) { z0[r] = 0.f; z1[r] = 0.f; }
  __builtin_amdgcn_s_setprio(1);
#pragma unroll
  for (int f = 0; f < 4; f++) {
    const bf16x8 a0 = *reinterpret_cast<const bf16x8*>(&Ksb[l31][f * 16 + hi * 8]);
    const bf16x8 a1 = *reinterpret_cast<const bf16x8*>(&Ksb[32 + l31][f * 16 + hi * 8]);
    z0 = __builtin_amdgcn_mfma_f32_32x32x16_bf16(a0, qf[f], z0, 0, 0, 0);
    z1 = __builtin_amdgcn_mfma_f32_32x32x16_bf16(a1, qf[f], z1, 0, 0, 0);
  }
  __builtin_amdgcn_s_setprio(0);
}

DEV void pv_half(const f32x16& z, int f0, const u16 (*Vsb)[72], int l31, int hi,
                 f32x16& o0, f32x16& o1) {
#pragma unroll
  for (int s = 0; s < 2; s++) {
    u32 w0 = pk2(z[s * 8 + 0], z[s * 8 + 1]);
    u32 w2 = pk2(z[s * 8 + 4], z[s * 8 + 5]);
    asm("v_permlane32_swap_b32 %0, %1" : "+v"(w0), "+v"(w2));
    u32 w1 = pk2(z[s * 8 + 2], z[s * 8 + 3]);
    u32 w3 = pk2(z[s * 8 + 6], z[s * 8 + 7]);
    asm("v_permlane32_swap_b32 %0, %1" : "+v"(w1), "+v"(w3));
    uint4 wv;
    wv.x = w0; wv.y = w1; wv.z = w2; wv.w = w3;
    const bf16x8 bp = __builtin_bit_cast(bf16x8, wv);
    const int f = f0 + s;
    const bf16x8 av0 = *reinterpret_cast<const bf16x8*>(&Vsb[l31][f * 16 + hi * 8]);
    const bf16x8 av1 = *reinterpret_cast<const bf16x8*>(&Vsb[32 + l31][f * 16 + hi * 8]);
    o0 = __builtin_amdgcn_mfma_f32_32x32x16_bf16(av0, bp, o0, 0, 0, 0);
    o1 = __builtin_amdgcn_mfma_f32_32x32x16_bf16(av1, bp, o1, 0, 0, 0);
  }
}

DEV void sm_pv(f32x16& z0, f32x16& z1, const u16 (*Vsb)[72], int l31, int hi,
               float& li, f32x16& o0, f32x16& o1) {
  float s0 = 0.f, s1 = 0.f, s2 = 0.f, s3 = 0.f;
#pragma unroll
  for (int r = 0; r < 16; r++) {
    const float p0 = __builtin_amdgcn_exp2f(z0[r]);
    const float p1 = __builtin_amdgcn_exp2f(z1[r]);
    z0[r] = p0; z1[r] = p1;
    if ((r & 3) == 0) { s0 += p0; s0 += p1; }
    else if ((r & 3) == 1) { s1 += p0; s1 += p1; }
    else if ((r & 3) == 2) { s2 += p0; s2 += p1; }
    else { s3 += p0; s3 += p1; }
  }
  li += (s0 + s1) + (s2 + s3);
  __builtin_amdgcn_s_setprio(1);
  pv_half(z0, 0, Vsb, l31, hi, o0, o1);
  pv_half(z1, 2, Vsb, l31, hi, o0, o1);
  __builtin_amdgcn_s_setprio(0);
}

// ---- flash attention: QBLK=128, 4 waves. T15 deferred softmax: iter k does
// QK(k) then softmax+PV(k-1) — the two are dependency-free, so QK's MFMAs
// overlap the previous tile's VALU (both pipes <40% busy in R14; serial chain
// was the stall). V triple-buffered (write V(k+1) while PV reads V(k-1):
// (k+1)%3 != (k-1)%3); K double-buffered. LDS 64.5KB -> still 2 blocks/CU.
// zE/zO named f32x16 pairs, hand-paired loop (rule #20). XCD swizzle, T12.
__global__ __launch_bounds__(256, 2) void k_attn(const u16* __restrict__ Qb,
                                                 const u16* __restrict__ Kb,
                                                 const u16* __restrict__ Vt,
                                                 u16* __restrict__ attnB) {
  __shared__ u16 Ks[2][64][72];  // [buf][key][dh]       18.4KB
  __shared__ u16 Vs[3][64][72];  // [buf][dh][key_local] 27.6KB
  __shared__ u16 Pl[4][32][72];  // epilogue-only (O staging) 18.4KB
  const int tid = threadIdx.x;
  const int lane = tid & 63, wave = tid >> 6;
  const int l31 = lane & 31, hi = lane >> 5;
  // XCD swizzle: nwg = 512, chunk = 64 (4 bh of 16 q-blocks per XCD)
  const int bid0 = blockIdx.x + 16 * blockIdx.y;
  const int bid = (bid0 & 7) * 64 + (bid0 >> 3);
  const int bh = bid >> 4;
  const int q0 = (bid & 15) * 128;
  const u16* Qh = Qb + (size_t)bh * S * 64;
  const u16* Kh = Kb + (size_t)bh * S * 64;
  const u16* Vh = Vt + (size_t)bh * 64 * S;
  const int qrow = q0 + wave * 32 + l31;
  bf16x8 qf[4];  // Q (pre-scaled by SCQ) as B-operand: n = lane&31 = q
#pragma unroll
  for (int f = 0; f < 4; f++)
    qf[f] = *reinterpret_cast<const bf16x8*>(&Qh[(size_t)qrow * 64 + f * 16 + hi * 8]);

  const int r0 = tid >> 3, c0 = (tid & 7) * 8;  // staging: 8 lanes x 16B per 128B row

  float li = 0.f;
  f32x16 o0, o1;  // O d-tiles: d = dt*32 + (reg&3)+8*(reg>>2)+4*hi
#pragma unroll
  for (int r = 0; r < 16; r++) { o0[r] = 0.f; o1[r] = 0.f; }
  f32x16 zE0, zE1, zO0, zO1;  // even/odd-iter score sets (named; no arrays)

  // prologue: tile 0 -> regs
  uint4 pk0 = *reinterpret_cast<const uint4*>(&Kh[(size_t)r0 * 64 + c0]);
  uint4 pk1 = *reinterpret_cast<const uint4*>(&Kh[(size_t)(r0 + 32) * 64 + c0]);
  uint4 pv0 = *reinterpret_cast<const uint4*>(&Vh[(size_t)r0 * S + c0]);
  uint4 pv1 = *reinterpret_cast<const uint4*>(&Vh[(size_t)(r0 + 32) * S + c0]);

  constexpr int NT = S / 64;  // 32 (even)

#define ATTN_STEP(KB, ZC0, ZC1, ZP0, ZP1, DO_CONS)                                \
  {                                                                               \
    const int cur_ = (KB) & 1, vb_ = (KB) % 3;                                    \
    *reinterpret_cast<uint4*>(&Ks[cur_][r0][c0]) = pk0;                           \
    *reinterpret_cast<uint4*>(&Ks[cur_][r0 + 32][c0]) = pk1;                      \
    *reinterpret_cast<uint4*>(&Vs[vb_][r0][c0]) = pv0;                            \
    *reinterpret_cast<uint4*>(&Vs[vb_][r0 + 32][c0]) = pv1;                       \
    if ((KB) + 1 < NT) {                                                          \
      const u16* Kn_ = Kh + (size_t)((KB) + 1) * 64 * 64;                         \
      const u16* Vn_ = Vh + (size_t)((KB) + 1) * 64;                              \
      pk0 = *reinterpret_cast<const uint4*>(&Kn_[(size_t)r0 * 64 + c0]);          \
      pk1 = *reinterpret_cast<const uint4*>(&Kn_[(size_t)(r0 + 32) * 64 + c0]);   \
      pv0 = *reinterpret_cast<const uint4*>(&Vn_[(size_t)r0 * S + c0]);           \
      pv1 = *reinterpret_cast<const uint4*>(&Vn_[(size_t)(r0 + 32) * S + c0]);    \
    }                                                                             \
    __syncthreads();                                                              \
    qk_produce(ZC0, ZC1, Ks[cur_], qf, l31, hi);                                  \
    if (DO_CONS) sm_pv(ZP0, ZP1, Vs[((KB) + 2) % 3], l31, hi, li, o0, o1);        \
  }

  for (int p = 0; p < NT / 2; p++) {
    ATTN_STEP(2 * p,     zE0, zE1, zO0, zO1, p > 0);
    ATTN_STEP(2 * p + 1, zO0, zO1, zE0, zE1, true);
  }
  // epilogue: consume last tile (NT-1, odd -> zO), V in buf (NT-1)%3
  sm_pv(zO0, zO1, Vs[(NT - 1) % 3], l31, hi, li, o0, o1);
#undef ATTN_STEP

  li += __shfl_xor(li, 32);
  const float inv = 1.f / li;
  // O -> Pl[q][d] (wave-private), then coalesced store
#pragma unroll
  for (int dt = 0; dt < 2; dt++) {
    const f32x16& od = dt ? o1 : o0;
#pragma unroll
    for (int g = 0; g < 4; g++) {
      uint2 ow;
      ow.x = pk2(od[g * 4 + 0] * inv, od[g * 4 + 1] * inv);
      ow.y = pk2(od[g * 4 + 2] * inv, od[g * 4 + 3] * inv);
      *reinterpret_cast<uint2*>(&Pl[wave][l31][dt * 32 + g * 8 + hi * 4]) = ow;
    }
  }
  const int b = bh >> 4, h = bh & 15;
  const int mbase = b * S + q0 + wave * 32;
  const int qr = lane >> 1, ch = (lane & 1) * 32;
  u16* dst = &attnB[(size_t)(mbase + qr) * D + h * 64 + ch];
#pragma unroll
  for (int c = 0; c < 4; c++)
    reinterpret_cast<uint4*>(dst)[c] = *reinterpret_cast<const uint4*>(&Pl[wave][qr][ch + c * 8]);
}

extern "C" void kernel_launch(void* const* d_in, const int* in_sizes, int n_in,
                              void* d_out, int out_size, void* d_ws, size_t ws_size,
                              hipStream_t stream) {
  const float* x = (const float*)d_in[0];
  const float* Wqkv = (const float*)d_in[1];
  const float* bqkv = (const float*)d_in[2];
  const float* Wout = (const float*)d_in[3];
  const float* bout = (const float*)d_in[4];
  float* out = (float*)d_out;

  char* p = (char*)d_ws;
  u16* WoutT = (u16*)p; p += (size_t)1024 * 1024 * 2;     // 2MB  (live thru gemm2)
  u16* attnB = (u16*)p; p += (size_t)4096 * 1024 * 2;     // 8MB  (live thru gemm2)
  u16* Xb = (u16*)p;    p += (size_t)4096 * 1024 * 2;     // 8MB  (dead after gemm0)
  u16* WqkvT = (u16*)p; p += (size_t)3072 * 1024 * 2;     // 6MB  (dead after gemm0)
  u16* Vt = (u16*)p;    p += (size_t)32 * 64 * 2048 * 2;  // 8MB  (dead after attn)
  u16* Qb = (u16*)p;    p += (size_t)32 * 2048 * 64 * 2;  // 8MB  (dead after attn)
  u16* Kb = (u16*)p;    p += (size_t)32 * 2048 * 64 * 2;  // 8MB  (dead after attn)

  k_prep<<<4096 + 3072 + 1024, 256, 0, stream>>>(x, Xb, Wqkv, WqkvT, Wout, WoutT);
  k_gemm0<<<dim3(3072 / 128, 4096 / 128), 256, 0, stream>>>(
      Xb, WqkvT, bqkv, 4096, 3072, 1024, Qb, Kb, Vt);
  k_attn<<<dim3(2048 / 128, 32), 256, 0, stream>>>(Qb, Kb, Vt, attnB);
  k_gemm2<<<dim3(1024 / 64, 4096 / 128), 256, 0, stream>>>(attnB, WoutT, bout, out);
}